// Round 1
// baseline (66865.845 us; speedup 1.0000x reference)
//
#include <hip/hip_runtime.h>
#include <hip/hip_bf16.h>

#define DMODEL 768
#define HD     64
#define NH     12
#define SEQL   81
#define BATCH  256
#define NTOK   (BATCH*SEQL)   /* 20736 */
#define FFDIM  3072
#define NLAYER 12

// ----------------------------- reductions -----------------------------
__device__ inline float wave_sum(float v) {
#pragma unroll
    for (int o = 32; o > 0; o >>= 1) v += __shfl_down(v, o, 64);
    return v;
}

// 256-thread block: sum two values
__device__ inline void block_sum2(float& a, float& b, float* red) {
    a = wave_sum(a);
    b = wave_sum(b);
    int lane = threadIdx.x & 63, wid = threadIdx.x >> 6;
    if (lane == 0) { red[wid] = a; red[4 + wid] = b; }
    __syncthreads();
    a = red[0] + red[1] + red[2] + red[3];
    b = red[4] + red[5] + red[6] + red[7];
    __syncthreads();
}

// ----------------------------- embedding + LN -----------------------------
__global__ __launch_bounds__(256) void embed_ln_kernel(
    const int* __restrict__ ids, const float* __restrict__ wemb,
    const float* __restrict__ pemb, const float* __restrict__ g,
    const float* __restrict__ b, float* __restrict__ out) {
    __shared__ float red[8];
    int tok = blockIdx.x;
    int s = tok % SEQL;
    long base = (long)ids[tok] * DMODEL;
    float vals[3];
    float sum = 0.f, sq = 0.f;
#pragma unroll
    for (int i = 0; i < 3; ++i) {
        int c = threadIdx.x + i * 256;
        float x = wemb[base + c] + pemb[s * DMODEL + c];
        vals[i] = x; sum += x; sq += x * x;
    }
    block_sum2(sum, sq, red);
    float mean = sum * (1.0f / DMODEL);
    float inv = rsqrtf(sq * (1.0f / DMODEL) - mean * mean + 1e-5f);
#pragma unroll
    for (int i = 0; i < 3; ++i) {
        int c = threadIdx.x + i * 256;
        out[(long)tok * DMODEL + c] = (vals[i] - mean) * inv * g[c] + b[c];
    }
}

// h = LN(h + r) * g + b   (in place on h)
__global__ __launch_bounds__(256) void add_ln_kernel(
    float* __restrict__ h, const float* __restrict__ r,
    const float* __restrict__ g, const float* __restrict__ b) {
    __shared__ float red[8];
    long base = (long)blockIdx.x * DMODEL;
    float vals[3];
    float sum = 0.f, sq = 0.f;
#pragma unroll
    for (int i = 0; i < 3; ++i) {
        int c = threadIdx.x + i * 256;
        float x = h[base + c] + r[base + c];
        vals[i] = x; sum += x; sq += x * x;
    }
    block_sum2(sum, sq, red);
    float mean = sum * (1.0f / DMODEL);
    float inv = rsqrtf(sq * (1.0f / DMODEL) - mean * mean + 1e-5f);
#pragma unroll
    for (int i = 0; i < 3; ++i) {
        int c = threadIdx.x + i * 256;
        h[base + c] = (vals[i] - mean) * inv * g[c] + b[c];
    }
}

// ----------------------------- fp32 tiled GEMM -----------------------------
// C[M,N] = act( (A[M,K] @ B[K,N] + bias[N]) * scale )
// requires M%64==0, N%64==0, K%16==0.  ACT: 0=none, 1=exact GELU
template <int ACT>
__global__ __launch_bounds__(256) void gemm_kernel(
    const float* __restrict__ A, const float* __restrict__ B,
    const float* __restrict__ bias, float* __restrict__ C,
    int M, int N, int K, float scale) {
    __shared__ float As[16][68];
    __shared__ float Bs[16][68];
    const int tx = threadIdx.x & 15, ty = threadIdx.x >> 4;
    const int m0 = blockIdx.y * 64, n0 = blockIdx.x * 64;
    float acc[4][4] = {};
    for (int k0 = 0; k0 < K; k0 += 16) {
#pragma unroll
        for (int i = 0; i < 4; ++i) {
            int idx = threadIdx.x + i * 256;
            int mi = idx >> 4, kk = idx & 15;
            As[kk][mi] = A[(long)(m0 + mi) * K + k0 + kk];
            int kk2 = idx >> 6, ni = idx & 63;
            Bs[kk2][ni] = B[(long)(k0 + kk2) * N + n0 + ni];
        }
        __syncthreads();
#pragma unroll
        for (int kk = 0; kk < 16; ++kk) {
            float a0[4], b0[4];
#pragma unroll
            for (int i = 0; i < 4; ++i) a0[i] = As[kk][ty * 4 + i];
#pragma unroll
            for (int j = 0; j < 4; ++j) b0[j] = Bs[kk][tx * 4 + j];
#pragma unroll
            for (int i = 0; i < 4; ++i)
#pragma unroll
                for (int j = 0; j < 4; ++j)
                    acc[i][j] += a0[i] * b0[j];
        }
        __syncthreads();
    }
#pragma unroll
    for (int i = 0; i < 4; ++i) {
        int m = m0 + ty * 4 + i;
#pragma unroll
        for (int j = 0; j < 4; ++j) {
            int n = n0 + tx * 4 + j;
            float v = (acc[i][j] + bias[n]) * scale;
            if (ACT == 1) v = 0.5f * v * (1.0f + erff(v * 0.70710678118654752f));
            C[(long)m * N + n] = v;
        }
    }
}

// ----------------------------- fused attention -----------------------------
// one block per (b, h); q already scaled by 0.125
__global__ __launch_bounds__(256) void attn_kernel(
    const float* __restrict__ q, const float* __restrict__ k,
    const float* __restrict__ v, float* __restrict__ o) {
    __shared__ float qs[SEQL][64];
    __shared__ float ks[SEQL][65];   // pad: scores read ks with stride-64 lane pattern
    __shared__ float vs[SEQL][64];
    __shared__ float sc[SEQL][SEQL];
    int b = blockIdx.x / NH, h = blockIdx.x % NH;
    long base = ((long)b * SEQL) * DMODEL + h * HD;
    for (int idx = threadIdx.x; idx < SEQL * HD; idx += 256) {
        int s = idx >> 6, d = idx & 63;
        qs[s][d] = q[base + (long)s * DMODEL + d];
        ks[s][d] = k[base + (long)s * DMODEL + d];
        vs[s][d] = v[base + (long)s * DMODEL + d];
    }
    __syncthreads();
    for (int e = threadIdx.x; e < SEQL * SEQL; e += 256) {
        int qi = e / SEQL, kj = e % SEQL;
        float dot = 0.f;
#pragma unroll
        for (int d = 0; d < HD; ++d) dot += qs[qi][d] * ks[kj][d];
        sc[qi][kj] = dot;
    }
    __syncthreads();
    if (threadIdx.x < SEQL) {
        int r = threadIdx.x;
        float mx = -1e30f;
        for (int j = 0; j < SEQL; ++j) mx = fmaxf(mx, sc[r][j]);
        float ssum = 0.f;
        for (int j = 0; j < SEQL; ++j) { float e2 = expf(sc[r][j] - mx); sc[r][j] = e2; ssum += e2; }
        float invs = 1.0f / ssum;
        for (int j = 0; j < SEQL; ++j) sc[r][j] *= invs;
    }
    __syncthreads();
    for (int e = threadIdx.x; e < SEQL * HD; e += 256) {
        int s = e >> 6, d = e & 63;
        float acc = 0.f;
        for (int j = 0; j < SEQL; ++j) acc += sc[s][j] * vs[j][d];
        o[base + (long)s * DMODEL + d] = acc;
    }
}

// ----------------------------- conv head -----------------------------
// conv0: x=[B,81,768] viewed as [B, C=768, T=81]; out [B,128,37]; k=8 s=2; +BN+ReLU
__global__ void conv0_kernel(const float* __restrict__ x, const float* __restrict__ w,
                             const float* __restrict__ cb, const float* __restrict__ g,
                             const float* __restrict__ bb, const float* __restrict__ bm,
                             const float* __restrict__ bv, float* __restrict__ out) {
    int idx = blockIdx.x * blockDim.x + threadIdx.x;
    if (idx >= BATCH * 128 * 37) return;
    int t = idx % 37, o = (idx / 37) % 128, b = idx / (37 * 128);
    float acc = cb[o];
    const float* wo = w + (long)o * 768 * 8;
    const float* xb = x + (long)b * SEQL * DMODEL;
    for (int c = 0; c < 768; ++c) {
#pragma unroll
        for (int kk = 0; kk < 8; ++kk)
            acc += xb[(2 * t + kk) * DMODEL + c] * wo[c * 8 + kk];
    }
    float y = (acc - bm[o]) * g[o] * rsqrtf(bv[o] + 1e-5f) + bb[o];
    out[idx] = fmaxf(y, 0.0f);
}

// conv1: in [B,128,35] -> out [B,64,14]; k=8 s=2; +BN+ReLU
__global__ void conv1_kernel(const float* __restrict__ x, const float* __restrict__ w,
                             const float* __restrict__ cb, const float* __restrict__ g,
                             const float* __restrict__ bb, const float* __restrict__ bm,
                             const float* __restrict__ bv, float* __restrict__ out) {
    int idx = blockIdx.x * blockDim.x + threadIdx.x;
    if (idx >= BATCH * 64 * 14) return;
    int t = idx % 14, o = (idx / 14) % 64, b = idx / (14 * 64);
    float acc = cb[o];
    const float* wo = w + (long)o * 128 * 8;
    const float* xb = x + (long)b * 128 * 35;
    for (int c = 0; c < 128; ++c) {
#pragma unroll
        for (int kk = 0; kk < 8; ++kk)
            acc += xb[c * 35 + 2 * t + kk] * wo[c * 8 + kk];
    }
    float y = (acc - bm[o]) * g[o] * rsqrtf(bv[o] + 1e-5f) + bb[o];
    out[idx] = fmaxf(y, 0.0f);
}

// conv2: in [B,64,12] -> out [B,32,5]; k=3 s=2; +BN+ReLU
__global__ void conv2_kernel(const float* __restrict__ x, const float* __restrict__ w,
                             const float* __restrict__ cb, const float* __restrict__ g,
                             const float* __restrict__ bb, const float* __restrict__ bm,
                             const float* __restrict__ bv, float* __restrict__ out) {
    int idx = blockIdx.x * blockDim.x + threadIdx.x;
    if (idx >= BATCH * 32 * 5) return;
    int t = idx % 5, o = (idx / 5) % 32, b = idx / (5 * 32);
    float acc = cb[o];
    const float* wo = w + (long)o * 64 * 3;
    const float* xb = x + (long)b * 64 * 12;
    for (int c = 0; c < 64; ++c) {
#pragma unroll
        for (int kk = 0; kk < 3; ++kk)
            acc += xb[c * 12 + 2 * t + kk] * wo[c * 3 + kk];
    }
    float y = (acc - bm[o]) * g[o] * rsqrtf(bv[o] + 1e-5f) + bb[o];
    out[idx] = fmaxf(y, 0.0f);
}

// maxpool k=3 s=1 over last dim: in [B,C,Tin] -> out [B,C,Tin-2]
__global__ void pool_kernel(const float* __restrict__ in, float* __restrict__ out,
                            int C, int Tin) {
    int Tout = Tin - 2;
    int idx = blockIdx.x * blockDim.x + threadIdx.x;
    if (idx >= BATCH * C * Tout) return;
    int t = idx % Tout;
    int co = idx / Tout;
    const float* p = in + (long)co * Tin + t;
    out[idx] = fmaxf(fmaxf(p[0], p[1]), p[2]);
}

// dense head: x [B,96] -> relu(x@d1w.T+d1b)[32] -> @d2w.T+d2b -> sigmoid
__global__ __launch_bounds__(64) void head_kernel(
    const float* __restrict__ x, const float* __restrict__ w1,
    const float* __restrict__ b1, const float* __restrict__ w2,
    const float* __restrict__ b2, float* __restrict__ out) {
    int b = blockIdx.x;
    int j = threadIdx.x;
    float y = 0.f;
    if (j < 32) {
        float acc = b1[j];
        const float* xb = x + b * 96;
        for (int i = 0; i < 96; ++i) acc += xb[i] * w1[j * 96 + i];
        y = fmaxf(acc, 0.0f) * w2[j];
    }
#pragma unroll
    for (int o = 32; o > 0; o >>= 1) y += __shfl_down(y, o, 64);
    if (j == 0) out[b] = 1.0f / (1.0f + expf(-(y + b2[0])));
}

// ----------------------------- launch -----------------------------
extern "C" void kernel_launch(void* const* d_in, const int* in_sizes, int n_in,
                              void* d_out, int out_size, void* d_ws, size_t ws_size,
                              hipStream_t stream) {
    const int*   ids  = (const int*)d_in[0];
    const float* wemb = (const float*)d_in[1];
    const float* pemb = (const float*)d_in[2];
    const float* elng = (const float*)d_in[3];
    const float* elnb = (const float*)d_in[4];
    const float* wq = (const float*)d_in[5];
    const float* bq = (const float*)d_in[6];
    const float* wk = (const float*)d_in[7];
    const float* bk = (const float*)d_in[8];
    const float* wv = (const float*)d_in[9];
    const float* bv = (const float*)d_in[10];
    const float* wo = (const float*)d_in[11];
    const float* bo = (const float*)d_in[12];
    const float* ln1g = (const float*)d_in[13];
    const float* ln1b = (const float*)d_in[14];
    const float* w1 = (const float*)d_in[15];
    const float* b1 = (const float*)d_in[16];
    const float* w2 = (const float*)d_in[17];
    const float* b2 = (const float*)d_in[18];
    const float* ln2g = (const float*)d_in[19];
    const float* ln2b = (const float*)d_in[20];
    const float* c0w = (const float*)d_in[21];
    const float* c0b = (const float*)d_in[22];
    const float* g0 = (const float*)d_in[23];
    const float* bb0 = (const float*)d_in[24];
    const float* m0 = (const float*)d_in[25];
    const float* v0 = (const float*)d_in[26];
    const float* c1w = (const float*)d_in[27];
    const float* c1b = (const float*)d_in[28];
    const float* g1 = (const float*)d_in[29];
    const float* bb1 = (const float*)d_in[30];
    const float* m1 = (const float*)d_in[31];
    const float* v1 = (const float*)d_in[32];
    const float* c2w = (const float*)d_in[33];
    const float* c2b = (const float*)d_in[34];
    const float* g2 = (const float*)d_in[35];
    const float* bb2 = (const float*)d_in[36];
    const float* m2 = (const float*)d_in[37];
    const float* v2 = (const float*)d_in[38];
    const float* d1w = (const float*)d_in[39];
    const float* d1b = (const float*)d_in[40];
    const float* d2w = (const float*)d_in[41];
    const float* d2b = (const float*)d_in[42];
    (void)in_sizes; (void)n_in; (void)out_size; (void)ws_size;

    const size_t SZ = (size_t)NTOK * DMODEL;  // 15,925,248 floats
    float* h  = (float*)d_ws;
    float* qb = h + SZ;
    float* kb = qb + SZ;   // also reused as FFN-intermediate chunk [5184,3072]
    float* vb = kb + SZ;
    float* tb = vb + SZ;
    float* c0 = tb + SZ;
    float* p0 = c0 + (size_t)BATCH * 128 * 37;
    float* c1 = p0 + (size_t)BATCH * 128 * 35;
    float* p1 = c1 + (size_t)BATCH * 64 * 14;
    float* c2 = p1 + (size_t)BATCH * 64 * 12;
    float* p2 = c2 + (size_t)BATCH * 32 * 5;

    embed_ln_kernel<<<NTOK, 256, 0, stream>>>(ids, wemb, pemb, elng, elnb, h);

    const dim3 gqkv(DMODEL / 64, NTOK / 64);      // 12 x 324
    const dim3 gf1(FFDIM / 64, 5184 / 64);        // 48 x 81
    const dim3 gf2(DMODEL / 64, 5184 / 64);       // 12 x 81

    for (int l = 0; l < NLAYER; ++l) {
        const float* wq_l = wq + (size_t)l * DMODEL * DMODEL;
        const float* wk_l = wk + (size_t)l * DMODEL * DMODEL;
        const float* wv_l = wv + (size_t)l * DMODEL * DMODEL;
        const float* wo_l = wo + (size_t)l * DMODEL * DMODEL;
        const float* w1_l = w1 + (size_t)l * DMODEL * FFDIM;
        const float* w2_l = w2 + (size_t)l * FFDIM * DMODEL;

        gemm_kernel<0><<<gqkv, 256, 0, stream>>>(h, wq_l, bq + l * DMODEL, qb, NTOK, DMODEL, DMODEL, 0.125f);
        gemm_kernel<0><<<gqkv, 256, 0, stream>>>(h, wk_l, bk + l * DMODEL, kb, NTOK, DMODEL, DMODEL, 1.0f);
        gemm_kernel<0><<<gqkv, 256, 0, stream>>>(h, wv_l, bv + l * DMODEL, vb, NTOK, DMODEL, DMODEL, 1.0f);
        attn_kernel<<<BATCH * NH, 256, 0, stream>>>(qb, kb, vb, tb);
        gemm_kernel<0><<<gqkv, 256, 0, stream>>>(tb, wo_l, bo + l * DMODEL, qb, NTOK, DMODEL, DMODEL, 1.0f);
        add_ln_kernel<<<NTOK, 256, 0, stream>>>(h, qb, ln1g + l * DMODEL, ln1b + l * DMODEL);

        // FFN in 4 row-chunks of 5184; intermediate reuses kb
        for (int ch = 0; ch < 4; ++ch) {
            const float* hc = h + (size_t)ch * 5184 * DMODEL;
            float* tc = tb + (size_t)ch * 5184 * DMODEL;
            gemm_kernel<1><<<gf1, 256, 0, stream>>>(hc, w1_l, b1 + l * FFDIM, kb, 5184, FFDIM, DMODEL, 1.0f);
            gemm_kernel<0><<<gf2, 256, 0, stream>>>(kb, w2_l, b2 + l * DMODEL, tc, 5184, DMODEL, FFDIM, 1.0f);
        }
        add_ln_kernel<<<NTOK, 256, 0, stream>>>(h, tb, ln2g + l * DMODEL, ln2b + l * DMODEL);
    }

    // CNN / MLP head
    {
        int n = BATCH * 128 * 37;
        conv0_kernel<<<(n + 255) / 256, 256, 0, stream>>>(h, c0w, c0b, g0, bb0, m0, v0, c0);
        n = BATCH * 128 * 35;
        pool_kernel<<<(n + 255) / 256, 256, 0, stream>>>(c0, p0, 128, 37);
        n = BATCH * 64 * 14;
        conv1_kernel<<<(n + 255) / 256, 256, 0, stream>>>(p0, c1w, c1b, g1, bb1, m1, v1, c1);
        n = BATCH * 64 * 12;
        pool_kernel<<<(n + 255) / 256, 256, 0, stream>>>(c1, p1, 64, 14);
        n = BATCH * 32 * 5;
        conv2_kernel<<<(n + 255) / 256, 256, 0, stream>>>(p1, c2w, c2b, g2, bb2, m2, v2, c2);
        n = BATCH * 32 * 3;
        pool_kernel<<<(n + 255) / 256, 256, 0, stream>>>(c2, p2, 32, 5);
        head_kernel<<<BATCH, 64, 0, stream>>>(p2, d1w, d1b, d2w, d2b, (float*)d_out);
    }
}

// Round 2
// 15555.994 us; speedup vs baseline: 4.2984x; 4.2984x over previous
//
#include <hip/hip_runtime.h>
#include <hip/hip_bf16.h>

#define DMODEL 768
#define HD     64
#define NH     12
#define SEQL   81
#define BATCH  256
#define NTOK   (BATCH*SEQL)   /* 20736 */
#define FFDIM  3072
#define NLAYER 12
#define FFCH   6912           /* FFN row chunk: 3 chunks of 54 M-tiles */

typedef __bf16 bf16x8 __attribute__((ext_vector_type(8)));
typedef float  f32x4  __attribute__((ext_vector_type(4)));

// bf16 helpers (RNE)
__device__ __forceinline__ float bf2f(ushort u) {
    union { float f; unsigned u; } c; c.u = ((unsigned)u) << 16; return c.f;
}
__device__ __forceinline__ ushort f2bf(float f) {
    union { float f; unsigned u; } c; c.f = f;
    unsigned x = c.u;
    unsigned r = (x + 0x7fffu + ((x >> 16) & 1u)) >> 16;
    return (ushort)r;
}

// XOR swizzle of k-groups (8 elems) within each 32-col block, keyed by row.
// Applied by ALL writers of GEMM-A bf16 buffers and by the GEMM LDS read.
__device__ __forceinline__ int swz_col(int m, int c) {
    return (c & ~31) | ((((c >> 3) & 3) ^ ((m >> 1) & 3)) << 3) | (c & 7);
}

#define GLL(gptr, lptr) __builtin_amdgcn_global_load_lds( \
    (const __attribute__((address_space(1))) void*)(gptr), \
    (__attribute__((address_space(3))) void*)(lptr), 16, 0, 0)

// ----------------------------- reductions -----------------------------
__device__ __forceinline__ float wave_sum(float v) {
#pragma unroll
    for (int o = 32; o > 0; o >>= 1) v += __shfl_down(v, o, 64);
    return v;
}
__device__ __forceinline__ float wave_max(float v) {
#pragma unroll
    for (int o = 32; o > 0; o >>= 1) v = fmaxf(v, __shfl_xor(v, o, 64));
    return v;
}
__device__ __forceinline__ float wave_sum_x(float v) {
#pragma unroll
    for (int o = 32; o > 0; o >>= 1) v += __shfl_xor(v, o, 64);
    return v;
}

__device__ __forceinline__ void block_sum2(float& a, float& b, float* red) {
    a = wave_sum(a);
    b = wave_sum(b);
    int lane = threadIdx.x & 63, wid = threadIdx.x >> 6;
    if (lane == 0) { red[wid] = a; red[4 + wid] = b; }
    __syncthreads();
    a = red[0] + red[1] + red[2] + red[3];
    b = red[4] + red[5] + red[6] + red[7];
    __syncthreads();
}

// ----------------------------- embedding + LN -----------------------------
__global__ __launch_bounds__(256) void embed_ln_kernel(
    const int* __restrict__ ids, const float* __restrict__ wemb,
    const float* __restrict__ pemb, const float* __restrict__ g,
    const float* __restrict__ b, float* __restrict__ out,
    ushort* __restrict__ outb) {
    __shared__ float red[8];
    int tok = blockIdx.x;
    int s = tok % SEQL;
    long base = (long)ids[tok] * DMODEL;
    float vals[3];
    float sum = 0.f, sq = 0.f;
#pragma unroll
    for (int i = 0; i < 3; ++i) {
        int c = threadIdx.x + i * 256;
        float x = wemb[base + c] + pemb[s * DMODEL + c];
        vals[i] = x; sum += x; sq += x * x;
    }
    block_sum2(sum, sq, red);
    float mean = sum * (1.0f / DMODEL);
    float inv = rsqrtf(sq * (1.0f / DMODEL) - mean * mean + 1e-5f);
#pragma unroll
    for (int i = 0; i < 3; ++i) {
        int c = threadIdx.x + i * 256;
        float y = (vals[i] - mean) * inv * g[c] + b[c];
        out[(size_t)tok * DMODEL + c] = y;
        outb[(size_t)tok * DMODEL + swz_col(tok, c)] = f2bf(y);
    }
}

// h = LN(h + r); writes fp32 h and swizzled bf16 hb
__global__ __launch_bounds__(256) void add_ln_kernel(
    float* __restrict__ h, const ushort* __restrict__ r,
    const float* __restrict__ g, const float* __restrict__ b,
    ushort* __restrict__ hb) {
    __shared__ float red[8];
    int tok = blockIdx.x;
    size_t base = (size_t)tok * DMODEL;
    float vals[3];
    float sum = 0.f, sq = 0.f;
#pragma unroll
    for (int i = 0; i < 3; ++i) {
        int c = threadIdx.x + i * 256;
        float x = h[base + c] + bf2f(r[base + c]);
        vals[i] = x; sum += x; sq += x * x;
    }
    block_sum2(sum, sq, red);
    float mean = sum * (1.0f / DMODEL);
    float inv = rsqrtf(sq * (1.0f / DMODEL) - mean * mean + 1e-5f);
#pragma unroll
    for (int i = 0; i < 3; ++i) {
        int c = threadIdx.x + i * 256;
        float y = (vals[i] - mean) * inv * g[c] + b[c];
        h[base + c] = y;
        hb[base + swz_col(tok, c)] = f2bf(y);
    }
}

// ----------------------------- weight conversion -----------------------------
// fp32 [K][N] row-major  ->  bf16 MFMA layout: out[(k>>3)*N*8 + n*8 + (k&7)]
__global__ __launch_bounds__(256) void convw_kernel(
    const float* __restrict__ in, ushort* __restrict__ out, int K, int N) {
    int idx = blockIdx.x * 256 + threadIdx.x;
    if (idx >= K * N) return;
    int k = idx / N, n = idx - k * N;
    out[(size_t)(k >> 3) * N * 8 + n * 8 + (k & 7)] = f2bf(in[idx]);
}

// ----------------------------- bf16 MFMA GEMM -----------------------------
// C[M,N] (bf16) = act((A[M,K](bf16, swizzled) @ B(bf16, MFMA layout) + bias)*scale)
// BM=BN=128, BK=32, 256 threads (4 waves, 2x2 of 64x64). M%128==0, N%128==0, K%32==0.
__device__ __forceinline__ void gemm_stage(
    const ushort* __restrict__ A, const ushort* __restrict__ B,
    ushort* Abuf, ushort* Bbuf, int tid, int w,
    int m0, int n0, int kt, int K, int N) {
    int r0 = tid >> 2;
    int ko = (tid & 3) << 3;
    const ushort* ga0 = A + (size_t)(m0 + r0) * K + kt * 32 + ko;
    ushort* la = Abuf + (w * 64) * 8;
    GLL(ga0, la);
    GLL(ga0 + (size_t)64 * K, la + 2048);
    int g0 = tid >> 7, nn0 = tid & 127;
    const ushort* gb0 = B + ((size_t)(kt * 4 + g0) * N + n0 + nn0) * 8;
    int li1 = 256 + tid;
    int g1 = li1 >> 7, nn1 = li1 & 127;
    const ushort* gb1 = B + ((size_t)(kt * 4 + g1) * N + n0 + nn1) * 8;
    ushort* lb = Bbuf + (w * 64) * 8;
    GLL(gb0, lb);
    GLL(gb1, lb + 2048);
}

template <int ACT, int SWZ_OUT>
__global__ __launch_bounds__(256) void gemm_bf16(
    const ushort* __restrict__ A, const ushort* __restrict__ B,
    const float* __restrict__ bias, ushort* __restrict__ C,
    int M, int N, int K, float scale, int ntn) {
    __shared__ ushort Abuf[2][128 * 32];
    __shared__ ushort Bbuf[2][32 * 128];

    // bijective XCD swizzle (m204)
    int nblk = gridDim.x;
    int q = nblk >> 3, rr = nblk & 7;
    int xcd = blockIdx.x & 7, sub = blockIdx.x >> 3;
    int wg = (xcd < rr ? xcd * (q + 1) : rr * (q + 1) + (xcd - rr) * q) + sub;
    int mt = wg / ntn, nt = wg - mt * ntn;
    int m0 = mt * 128, n0 = nt * 128;

    int tid = threadIdx.x;
    int w = tid >> 6, l = tid & 63;
    int wm = w >> 1, wn = w & 1;

    f32x4 acc[4][4];
#pragma unroll
    for (int i = 0; i < 4; ++i)
#pragma unroll
        for (int j = 0; j < 4; ++j)
            acc[i][j] = (f32x4){0.f, 0.f, 0.f, 0.f};

    const int KT = K >> 5;
    gemm_stage(A, B, Abuf[0], Bbuf[0], tid, w, m0, n0, 0, K, N);
    __syncthreads();
    int cur = 0;
    for (int kt = 0; kt < KT; ++kt) {
        if (kt + 1 < KT)
            gemm_stage(A, B, Abuf[cur ^ 1], Bbuf[cur ^ 1], tid, w, m0, n0, kt + 1, K, N);
        const char* Ab = (const char*)&Abuf[cur][0];
        const char* Bb = (const char*)&Bbuf[cur][0];
        bf16x8 af[4], bfv[4];
        int kg = l >> 4, c16 = l & 15;
#pragma unroll
        for (int mi = 0; mi < 4; ++mi) {
            int row = wm * 64 + mi * 16 + c16;
            int byt = row * 64 + ((kg ^ ((row >> 1) & 3)) << 4);
            af[mi] = *(const bf16x8*)(Ab + byt);
        }
#pragma unroll
        for (int ni = 0; ni < 4; ++ni) {
            int col = wn * 64 + ni * 16 + c16;
            int byt = kg * 2048 + col * 16;
            bfv[ni] = *(const bf16x8*)(Bb + byt);
        }
#pragma unroll
        for (int mi = 0; mi < 4; ++mi)
#pragma unroll
            for (int ni = 0; ni < 4; ++ni)
                acc[mi][ni] = __builtin_amdgcn_mfma_f32_16x16x32_bf16(
                    af[mi], bfv[ni], acc[mi][ni], 0, 0, 0);
        __syncthreads();
        cur ^= 1;
    }

    // epilogue: C/D layout col = lane&15, row = (lane>>4)*4 + reg
    int c16 = l & 15, rhi = (l >> 4) * 4;
#pragma unroll
    for (int ni = 0; ni < 4; ++ni) {
        int col = n0 + wn * 64 + ni * 16 + c16;
        float bvv = bias[col];
#pragma unroll
        for (int mi = 0; mi < 4; ++mi) {
#pragma unroll
            for (int r = 0; r < 4; ++r) {
                int row = m0 + wm * 64 + mi * 16 + rhi + r;
                float v = (acc[mi][ni][r] + bvv) * scale;
                if (ACT == 1) v = 0.5f * v * (1.0f + erff(v * 0.70710678118654752f));
                int cw = SWZ_OUT ? swz_col(row, col) : col;
                C[(size_t)row * N + cw] = f2bf(v);
            }
        }
    }
}

// ----------------------------- fused attention -----------------------------
// one block (4 waves) per (b,h); wave handles q-rows r = w, w+4, ...
__global__ __launch_bounds__(256) void attn_kernel(
    const ushort* __restrict__ q, const ushort* __restrict__ k,
    const ushort* __restrict__ v, ushort* __restrict__ o) {
    __shared__ float kst[64][91];   // K transposed: kst[d][s]
    __shared__ float vs[SEQL][64];
    int b = blockIdx.x / NH, h = blockIdx.x % NH;
    size_t base = (size_t)b * SEQL * DMODEL + h * HD;
    for (int idx = threadIdx.x; idx < SEQL * HD; idx += 256) {
        int s = idx >> 6, d = idx & 63;
        kst[d][s] = bf2f(k[base + (size_t)s * DMODEL + d]);
        vs[s][d] = bf2f(v[base + (size_t)s * DMODEL + d]);
    }
    __syncthreads();
    int w = threadIdx.x >> 6, l = threadIdx.x & 63;
    bool has2 = (l < SEQL - 64);
    int j2 = has2 ? 64 + l : 80;
    for (int r = w; r < SEQL; r += 4) {
        float qd = bf2f(q[base + (size_t)r * DMODEL + l]);  // lane l holds q[r][l]
        float s0 = 0.f, s1 = 0.f;
#pragma unroll 8
        for (int d = 0; d < 64; ++d) {
            float qv = __shfl(qd, d, 64);
            s0 += qv * kst[d][l];
            s1 += qv * kst[d][j2];
        }
        if (!has2) s1 = -1e30f;
        float mx = wave_max(fmaxf(s0, s1));
        float p0 = expf(s0 - mx);
        float p1 = has2 ? expf(s1 - mx) : 0.f;
        float inv = 1.0f / wave_sum_x(p0 + p1);
        p0 *= inv; p1 *= inv;
        float acc = 0.f;
#pragma unroll 8
        for (int j = 0; j < 64; ++j)
            acc += __shfl(p0, j, 64) * vs[j][l];
#pragma unroll
        for (int j = 64; j < SEQL; ++j)
            acc += __shfl(p1, j - 64, 64) * vs[j][l];
        int tok = b * SEQL + r;
        o[(size_t)tok * DMODEL + swz_col(tok, h * HD + l)] = f2bf(acc);
    }
}

// ----------------------------- conv head -----------------------------
// conv0: block per batch; x=[B,81,768] as [B,C=768,T=81]; out [B,128,37]; k=8 s=2; +BN+ReLU
__global__ __launch_bounds__(256) void conv0_kernel(
    const float* __restrict__ x, const float* __restrict__ w,
    const float* __restrict__ cb, const float* __restrict__ g,
    const float* __restrict__ bb, const float* __restrict__ bm,
    const float* __restrict__ bv, float* __restrict__ out) {
    __shared__ float xs[SEQL][64];
    int b = blockIdx.x;
    int tid = threadIdx.x;
    int o = tid & 127, th = tid >> 7;   // wave-uniform th
    float acc[19];
#pragma unroll
    for (int j = 0; j < 19; ++j) acc[j] = 0.f;
    int nt = th ? 18 : 19;
    for (int c0 = 0; c0 < DMODEL; c0 += 64) {
        __syncthreads();
        for (int idx = tid; idx < SEQL * 64; idx += 256) {
            int s = idx >> 6, c = idx & 63;
            xs[s][c] = x[(size_t)b * SEQL * DMODEL + (size_t)s * DMODEL + c0 + c];
        }
        __syncthreads();
        for (int c = 0; c < 64; ++c) {
            const float* wp = w + (size_t)o * (DMODEL * 8) + (size_t)(c0 + c) * 8;
#pragma unroll
            for (int kk = 0; kk < 8; ++kk) {
                float wv = wp[kk];
#pragma unroll
                for (int j = 0; j < 19; ++j) {
                    if (j < nt) acc[j] += xs[2 * (th + 2 * j) + kk][c] * wv;
                }
            }
        }
    }
    float s = g[o] * rsqrtf(bv[o] + 1e-5f);
    float sh = bb[o] - bm[o] * s;
#pragma unroll
    for (int j = 0; j < 19; ++j) {
        if (j < nt) {
            int t = th + 2 * j;
            out[(size_t)b * 128 * 37 + (size_t)o * 37 + t] =
                fmaxf((acc[j] + cb[o]) * s + sh, 0.f);
        }
    }
}

// conv1: in [B,128,35] -> out [B,64,14]; k=8 s=2; +BN+ReLU
__global__ void conv1_kernel(const float* __restrict__ x, const float* __restrict__ w,
                             const float* __restrict__ cb, const float* __restrict__ g,
                             const float* __restrict__ bb, const float* __restrict__ bm,
                             const float* __restrict__ bv, float* __restrict__ out) {
    int idx = blockIdx.x * blockDim.x + threadIdx.x;
    if (idx >= BATCH * 64 * 14) return;
    int t = idx % 14, o = (idx / 14) % 64, b = idx / (14 * 64);
    float acc = cb[o];
    const float* wo = w + (long)o * 128 * 8;
    const float* xb = x + (long)b * 128 * 35;
    for (int c = 0; c < 128; ++c) {
#pragma unroll
        for (int kk = 0; kk < 8; ++kk)
            acc += xb[c * 35 + 2 * t + kk] * wo[c * 8 + kk];
    }
    float y = (acc - bm[o]) * g[o] * rsqrtf(bv[o] + 1e-5f) + bb[o];
    out[idx] = fmaxf(y, 0.0f);
}

// conv2: in [B,64,12] -> out [B,32,5]; k=3 s=2; +BN+ReLU
__global__ void conv2_kernel(const float* __restrict__ x, const float* __restrict__ w,
                             const float* __restrict__ cb, const float* __restrict__ g,
                             const float* __restrict__ bb, const float* __restrict__ bm,
                             const float* __restrict__ bv, float* __restrict__ out) {
    int idx = blockIdx.x * blockDim.x + threadIdx.x;
    if (idx >= BATCH * 32 * 5) return;
    int t = idx % 5, o = (idx / 5) % 32, b = idx / (5 * 32);
    float acc = cb[o];
    const float* wo = w + (long)o * 64 * 3;
    const float* xb = x + (long)b * 64 * 12;
    for (int c = 0; c < 64; ++c) {
#pragma unroll
        for (int kk = 0; kk < 3; ++kk)
            acc += xb[c * 12 + 2 * t + kk] * wo[c * 3 + kk];
    }
    float y = (acc - bm[o]) * g[o] * rsqrtf(bv[o] + 1e-5f) + bb[o];
    out[idx] = fmaxf(y, 0.0f);
}

__global__ void pool_kernel(const float* __restrict__ in, float* __restrict__ out,
                            int C, int Tin) {
    int Tout = Tin - 2;
    int idx = blockIdx.x * blockDim.x + threadIdx.x;
    if (idx >= BATCH * C * Tout) return;
    int t = idx % Tout;
    int co = idx / Tout;
    const float* p = in + (long)co * Tin + t;
    out[idx] = fmaxf(fmaxf(p[0], p[1]), p[2]);
}

__global__ __launch_bounds__(64) void head_kernel(
    const float* __restrict__ x, const float* __restrict__ w1,
    const float* __restrict__ b1, const float* __restrict__ w2,
    const float* __restrict__ b2, float* __restrict__ out) {
    int b = blockIdx.x;
    int j = threadIdx.x;
    float y = 0.f;
    if (j < 32) {
        float acc = b1[j];
        const float* xb = x + b * 96;
        for (int i = 0; i < 96; ++i) acc += xb[i] * w1[j * 96 + i];
        y = fmaxf(acc, 0.0f) * w2[j];
    }
#pragma unroll
    for (int o = 32; o > 0; o >>= 1) y += __shfl_down(y, o, 64);
    if (j == 0) out[b] = 1.0f / (1.0f + expf(-(y + b2[0])));
}

// ----------------------------- launch -----------------------------
extern "C" void kernel_launch(void* const* d_in, const int* in_sizes, int n_in,
                              void* d_out, int out_size, void* d_ws, size_t ws_size,
                              hipStream_t stream) {
    const int*   ids  = (const int*)d_in[0];
    const float* wemb = (const float*)d_in[1];
    const float* pemb = (const float*)d_in[2];
    const float* elng = (const float*)d_in[3];
    const float* elnb = (const float*)d_in[4];
    const float* wq = (const float*)d_in[5];
    const float* bq = (const float*)d_in[6];
    const float* wk = (const float*)d_in[7];
    const float* bk = (const float*)d_in[8];
    const float* wv = (const float*)d_in[9];
    const float* bv = (const float*)d_in[10];
    const float* wo = (const float*)d_in[11];
    const float* bo = (const float*)d_in[12];
    const float* ln1g = (const float*)d_in[13];
    const float* ln1b = (const float*)d_in[14];
    const float* w1 = (const float*)d_in[15];
    const float* b1 = (const float*)d_in[16];
    const float* w2 = (const float*)d_in[17];
    const float* b2 = (const float*)d_in[18];
    const float* ln2g = (const float*)d_in[19];
    const float* ln2b = (const float*)d_in[20];
    const float* c0w = (const float*)d_in[21];
    const float* c0b = (const float*)d_in[22];
    const float* g0 = (const float*)d_in[23];
    const float* bb0 = (const float*)d_in[24];
    const float* m0 = (const float*)d_in[25];
    const float* v0 = (const float*)d_in[26];
    const float* c1w = (const float*)d_in[27];
    const float* c1b = (const float*)d_in[28];
    const float* g1 = (const float*)d_in[29];
    const float* bb1 = (const float*)d_in[30];
    const float* m1 = (const float*)d_in[31];
    const float* v1 = (const float*)d_in[32];
    const float* c2w = (const float*)d_in[33];
    const float* c2b = (const float*)d_in[34];
    const float* g2 = (const float*)d_in[35];
    const float* bb2 = (const float*)d_in[36];
    const float* m2 = (const float*)d_in[37];
    const float* v2 = (const float*)d_in[38];
    const float* d1w = (const float*)d_in[39];
    const float* d1b = (const float*)d_in[40];
    const float* d2w = (const float*)d_in[41];
    const float* d2b = (const float*)d_in[42];
    (void)in_sizes; (void)n_in; (void)out_size; (void)ws_size;

    const size_t SZ = (size_t)NTOK * DMODEL;  // 15,925,248
    char* p = (char*)d_ws;
    float*  h   = (float*)p;  p += SZ * 4;
    ushort* hb  = (ushort*)p; p += SZ * 2;
    ushort* qb  = (ushort*)p; p += SZ * 2;
    ushort* kb  = (ushort*)p; p += SZ * 2;
    ushort* vb  = (ushort*)p; p += SZ * 2;
    ushort* ob  = (ushort*)p; p += SZ * 2;
    ushort* rb  = (ushort*)p; p += SZ * 2;
    ushort* ff  = (ushort*)p; p += (size_t)FFCH * FFDIM * 2;
    ushort* wqb = (ushort*)p; p += (size_t)DMODEL * DMODEL * 2;
    ushort* wkb = (ushort*)p; p += (size_t)DMODEL * DMODEL * 2;
    ushort* wvb = (ushort*)p; p += (size_t)DMODEL * DMODEL * 2;
    ushort* wob = (ushort*)p; p += (size_t)DMODEL * DMODEL * 2;
    ushort* w1b = (ushort*)p; p += (size_t)DMODEL * FFDIM * 2;
    ushort* w2b = (ushort*)p; p += (size_t)FFDIM * DMODEL * 2;
    float* c0 = (float*)p;  p += (size_t)BATCH * 128 * 37 * 4;
    float* p0 = (float*)p;  p += (size_t)BATCH * 128 * 35 * 4;
    float* c1 = (float*)p;  p += (size_t)BATCH * 64 * 14 * 4;
    float* p1 = (float*)p;  p += (size_t)BATCH * 64 * 12 * 4;
    float* c2 = (float*)p;  p += (size_t)BATCH * 32 * 5 * 4;
    float* p2 = (float*)p;

    embed_ln_kernel<<<NTOK, 256, 0, stream>>>(ids, wemb, pemb, elng, elnb, h, hb);

    const int NWG_QKV = (NTOK / 128) * (DMODEL / 128);   // 162*6 = 972
    const int NWG_F1  = (FFCH / 128) * (FFDIM / 128);    // 54*24 = 1296
    const int NWG_F2  = (FFCH / 128) * (DMODEL / 128);   // 54*6  = 324
    const int CWG_DD  = (DMODEL * DMODEL + 255) / 256;
    const int CWG_DF  = (DMODEL * FFDIM + 255) / 256;

    for (int l = 0; l < NLAYER; ++l) {
        convw_kernel<<<CWG_DD, 256, 0, stream>>>(wq + (size_t)l * DMODEL * DMODEL, wqb, DMODEL, DMODEL);
        convw_kernel<<<CWG_DD, 256, 0, stream>>>(wk + (size_t)l * DMODEL * DMODEL, wkb, DMODEL, DMODEL);
        convw_kernel<<<CWG_DD, 256, 0, stream>>>(wv + (size_t)l * DMODEL * DMODEL, wvb, DMODEL, DMODEL);
        convw_kernel<<<CWG_DD, 256, 0, stream>>>(wo + (size_t)l * DMODEL * DMODEL, wob, DMODEL, DMODEL);
        convw_kernel<<<CWG_DF, 256, 0, stream>>>(w1 + (size_t)l * DMODEL * FFDIM, w1b, DMODEL, FFDIM);
        convw_kernel<<<CWG_DF, 256, 0, stream>>>(w2 + (size_t)l * FFDIM * DMODEL, w2b, FFDIM, DMODEL);

        gemm_bf16<0, 0><<<NWG_QKV, 256, 0, stream>>>(hb, wqb, bq + (size_t)l * DMODEL, qb,
                                                     NTOK, DMODEL, DMODEL, 0.125f, DMODEL / 128);
        gemm_bf16<0, 0><<<NWG_QKV, 256, 0, stream>>>(hb, wkb, bk + (size_t)l * DMODEL, kb,
                                                     NTOK, DMODEL, DMODEL, 1.0f, DMODEL / 128);
        gemm_bf16<0, 0><<<NWG_QKV, 256, 0, stream>>>(hb, wvb, bv + (size_t)l * DMODEL, vb,
                                                     NTOK, DMODEL, DMODEL, 1.0f, DMODEL / 128);
        attn_kernel<<<BATCH * NH, 256, 0, stream>>>(qb, kb, vb, ob);
        gemm_bf16<0, 0><<<NWG_QKV, 256, 0, stream>>>(ob, wob, bo + (size_t)l * DMODEL, rb,
                                                     NTOK, DMODEL, DMODEL, 1.0f, DMODEL / 128);
        add_ln_kernel<<<NTOK, 256, 0, stream>>>(h, rb, ln1g + (size_t)l * DMODEL,
                                                ln1b + (size_t)l * DMODEL, hb);
        for (int ch = 0; ch < 3; ++ch) {
            const ushort* hc = hb + (size_t)ch * FFCH * DMODEL;
            ushort* rc = rb + (size_t)ch * FFCH * DMODEL;
            gemm_bf16<1, 1><<<NWG_F1, 256, 0, stream>>>(hc, w1b, b1 + (size_t)l * FFDIM, ff,
                                                        FFCH, FFDIM, DMODEL, 1.0f, FFDIM / 128);
            gemm_bf16<0, 0><<<NWG_F2, 256, 0, stream>>>(ff, w2b, b2 + (size_t)l * DMODEL, rc,
                                                        FFCH, DMODEL, FFDIM, 1.0f, DMODEL / 128);
        }
        add_ln_kernel<<<NTOK, 256, 0, stream>>>(h, rb, ln2g + (size_t)l * DMODEL,
                                                ln2b + (size_t)l * DMODEL, hb);
    }

    // CNN / MLP head
    {
        conv0_kernel<<<BATCH, 256, 0, stream>>>(h, c0w, c0b, g0, bb0, m0, v0, c0);
        int n = BATCH * 128 * 35;
        pool_kernel<<<(n + 255) / 256, 256, 0, stream>>>(c0, p0, 128, 37);
        n = BATCH * 64 * 14;
        conv1_kernel<<<(n + 255) / 256, 256, 0, stream>>>(p0, c1w, c1b, g1, bb1, m1, v1, c1);
        n = BATCH * 64 * 12;
        pool_kernel<<<(n + 255) / 256, 256, 0, stream>>>(c1, p1, 64, 14);
        n = BATCH * 32 * 5;
        conv2_kernel<<<(n + 255) / 256, 256, 0, stream>>>(p1, c2w, c2b, g2, bb2, m2, v2, c2);
        n = BATCH * 32 * 3;
        pool_kernel<<<(n + 255) / 256, 256, 0, stream>>>(c2, p2, 32, 5);
        head_kernel<<<BATCH, 64, 0, stream>>>(p2, d1w, d1b, d2w, d2b, (float*)d_out);
    }
}

// Round 3
// 13262.061 us; speedup vs baseline: 5.0419x; 1.1730x over previous
//
#include <hip/hip_runtime.h>
#include <hip/hip_bf16.h>

#define DMODEL 768
#define HD     64
#define NH     12
#define SEQL   81
#define BATCH  256
#define NTOK   (BATCH*SEQL)   /* 20736 */
#define FFDIM  3072
#define NLAYER 12
#define FFCH   6912           /* fallback FFN row chunk */

typedef __bf16 bf16x8 __attribute__((ext_vector_type(8)));
typedef float  f32x4  __attribute__((ext_vector_type(4)));

__device__ __forceinline__ float bf2f(ushort u) {
    union { float f; unsigned u; } c; c.u = ((unsigned)u) << 16; return c.f;
}
__device__ __forceinline__ ushort f2bf(float f) {
    union { float f; unsigned u; } c; c.f = f;
    unsigned x = c.u;
    unsigned r = (x + 0x7fffu + ((x >> 16) & 1u)) >> 16;
    return (ushort)r;
}

#define GLL(gptr, lptr) __builtin_amdgcn_global_load_lds( \
    (const __attribute__((address_space(1))) void*)(gptr), \
    (__attribute__((address_space(3))) void*)(lptr), 16, 0, 0)

// ----------------------------- reductions -----------------------------
__device__ __forceinline__ float wave_sum(float v) {
#pragma unroll
    for (int o = 32; o > 0; o >>= 1) v += __shfl_down(v, o, 64);
    return v;
}
__device__ __forceinline__ float wave_max(float v) {
#pragma unroll
    for (int o = 32; o > 0; o >>= 1) v = fmaxf(v, __shfl_xor(v, o, 64));
    return v;
}
__device__ __forceinline__ float wave_sum_x(float v) {
#pragma unroll
    for (int o = 32; o > 0; o >>= 1) v += __shfl_xor(v, o, 64);
    return v;
}

__device__ __forceinline__ void block_sum2_w4(float& a, float& b, float* red) {
    a = wave_sum(a); b = wave_sum(b);
    int lane = threadIdx.x & 63, wid = threadIdx.x >> 6;
    if (lane == 0) { red[wid] = a; red[4 + wid] = b; }
    __syncthreads();
    a = red[0] + red[1] + red[2] + red[3];
    b = red[4] + red[5] + red[6] + red[7];
    __syncthreads();
}
__device__ __forceinline__ void block_sum2_w3(float& a, float& b, float* red) {
    a = wave_sum(a); b = wave_sum(b);
    int lane = threadIdx.x & 63, wid = threadIdx.x >> 6;
    if (lane == 0) { red[wid] = a; red[3 + wid] = b; }
    __syncthreads();
    a = red[0] + red[1] + red[2];
    b = red[3] + red[4] + red[5];
    __syncthreads();
}

// ----------------------------- embedding + LN -----------------------------
__global__ __launch_bounds__(256) void embed_ln_kernel(
    const int* __restrict__ ids, const float* __restrict__ wemb,
    const float* __restrict__ pemb, const float* __restrict__ g,
    const float* __restrict__ b, float* __restrict__ out,
    ushort* __restrict__ outb) {
    __shared__ float red[8];
    int tok = blockIdx.x;
    int s = tok % SEQL;
    long base = (long)ids[tok] * DMODEL;
    float vals[3];
    float sum = 0.f, sq = 0.f;
#pragma unroll
    for (int i = 0; i < 3; ++i) {
        int c = threadIdx.x + i * 256;
        float x = wemb[base + c] + pemb[s * DMODEL + c];
        vals[i] = x; sum += x; sq += x * x;
    }
    block_sum2_w4(sum, sq, red);
    float mean = sum * (1.0f / DMODEL);
    float inv = rsqrtf(sq * (1.0f / DMODEL) - mean * mean + 1e-5f);
#pragma unroll
    for (int i = 0; i < 3; ++i) {
        int c = threadIdx.x + i * 256;
        float y = (vals[i] - mean) * inv * g[c] + b[c];
        out[(size_t)tok * DMODEL + c] = y;
        outb[(size_t)tok * DMODEL + c] = f2bf(y);
    }
}

// h = LN(h + r); writes fp32 h and plain bf16 hb. 192 threads, float4.
__global__ __launch_bounds__(192) void add_ln_kernel(
    float* __restrict__ h, const ushort* __restrict__ r,
    const float* __restrict__ g, const float* __restrict__ b,
    ushort* __restrict__ hb) {
    __shared__ float red[6];
    size_t base = (size_t)blockIdx.x * DMODEL;
    int c = threadIdx.x * 4;
    float4 hv = *(const float4*)(h + base + c);
    ushort4 rv = *(const ushort4*)(r + base + c);
    float vals[4];
    vals[0] = hv.x + bf2f(rv.x); vals[1] = hv.y + bf2f(rv.y);
    vals[2] = hv.z + bf2f(rv.z); vals[3] = hv.w + bf2f(rv.w);
    float sum = 0.f, sq = 0.f;
#pragma unroll
    for (int i = 0; i < 4; ++i) { sum += vals[i]; sq += vals[i] * vals[i]; }
    block_sum2_w3(sum, sq, red);
    float mean = sum * (1.0f / DMODEL);
    float inv = rsqrtf(sq * (1.0f / DMODEL) - mean * mean + 1e-5f);
    float4 gv = *(const float4*)(g + c);
    float4 bv = *(const float4*)(b + c);
    float y0 = (vals[0] - mean) * inv * gv.x + bv.x;
    float y1 = (vals[1] - mean) * inv * gv.y + bv.y;
    float y2 = (vals[2] - mean) * inv * gv.z + bv.z;
    float y3 = (vals[3] - mean) * inv * gv.w + bv.w;
    *(float4*)(h + base + c) = make_float4(y0, y1, y2, y3);
    ushort4 ov; ov.x = f2bf(y0); ov.y = f2bf(y1); ov.z = f2bf(y2); ov.w = f2bf(y3);
    *(ushort4*)(hb + base + c) = ov;
}

// ----------------------------- weight conversion (per layer, fused) -----------
// dst MFMA layout: out[(k>>3)*N*8 + n*8 + (k&7)]
#define SQ1 589824                 /* 768*768 */
#define SQ2 2359296                /* 768*3072 */
#define CW_TOTAL (4*SQ1 + 2*SQ2 + 2304)
__global__ __launch_bounds__(256) void convw_layer(
    const float* __restrict__ wq, const float* __restrict__ wk,
    const float* __restrict__ wv, const float* __restrict__ wo,
    const float* __restrict__ w1, const float* __restrict__ w2,
    const float* __restrict__ bq, const float* __restrict__ bk,
    const float* __restrict__ bvp,
    ushort* __restrict__ qkvw, ushort* __restrict__ wob,
    ushort* __restrict__ w1b, ushort* __restrict__ w2b,
    float* __restrict__ cbias) {
    for (int i = blockIdx.x * 256 + threadIdx.x; i < CW_TOTAL; i += gridDim.x * 256) {
        if (i < 3 * SQ1) {
            int widx = i / SQ1, j = i - widx * SQ1;
            const float* src = widx == 0 ? wq : (widx == 1 ? wk : wv);
            int k = j / 768, n = j - k * 768;
            qkvw[(size_t)(k >> 3) * 2304 * 8 + (widx * 768 + n) * 8 + (k & 7)] = f2bf(src[j]);
        } else if (i < 4 * SQ1) {
            int j = i - 3 * SQ1;
            int k = j / 768, n = j - k * 768;
            wob[(size_t)(k >> 3) * 768 * 8 + n * 8 + (k & 7)] = f2bf(wo[j]);
        } else if (i < 4 * SQ1 + SQ2) {
            int j = i - 4 * SQ1;
            int k = j / 3072, n = j - k * 3072;
            w1b[(size_t)(k >> 3) * 3072 * 8 + n * 8 + (k & 7)] = f2bf(w1[j]);
        } else if (i < 4 * SQ1 + 2 * SQ2) {
            int j = i - 4 * SQ1 - SQ2;
            int k = j / 768, n = j - k * 768;
            w2b[(size_t)(k >> 3) * 768 * 8 + n * 8 + (k & 7)] = f2bf(w2[j]);
        } else {
            int j = i - 4 * SQ1 - 2 * SQ2;
            cbias[j] = j < 768 ? bq[j] : (j < 1536 ? bk[j - 768] : bvp[j - 1536]);
        }
    }
}

// conv0 weights: w[o][c][kk] fp32 -> dst[kk][(c>>3)*1024 + o*8 + (c&7)] bf16
__global__ __launch_bounds__(256) void convw_c0(
    const float* __restrict__ w, ushort* __restrict__ dst) {
    int idx = blockIdx.x * 256 + threadIdx.x;
    if (idx >= 128 * 768 * 8) return;
    int o = idx / 6144, rem = idx - o * 6144, c = rem >> 3, kk = rem & 7;
    dst[(size_t)kk * 98304 + (size_t)(c >> 3) * 1024 + o * 8 + (c & 7)] = f2bf(w[idx]);
}

// ----------------------------- bf16 MFMA GEMM -----------------------------
// A plain [M][K] bf16; swizzle applied on the global source address (rule 21).
__device__ __forceinline__ void gemm_stage(
    const ushort* __restrict__ A, const ushort* __restrict__ B,
    ushort* Abuf, ushort* Bbuf, int tid,
    int m0, int n0, int kt, int K, int N) {
    int r0 = tid >> 2;
    int kgrp = (((tid & 3) ^ ((tid >> 3) & 3)) << 3);
    const ushort* ga0 = A + (size_t)(m0 + r0) * K + kt * 32 + kgrp;
    int w = tid >> 6;
    ushort* la = Abuf + (w * 64) * 8;
    GLL(ga0, la);
    GLL(ga0 + (size_t)64 * K, la + 2048);
    int g0 = tid >> 7, nn0 = tid & 127;
    const ushort* gb0 = B + ((size_t)(kt * 4 + g0) * N + n0 + nn0) * 8;
    int li1 = 256 + tid;
    int g1 = li1 >> 7, nn1 = li1 & 127;
    const ushort* gb1 = B + ((size_t)(kt * 4 + g1) * N + n0 + nn1) * 8;
    ushort* lb = Bbuf + (w * 64) * 8;
    GLL(gb0, lb);
    GLL(gb1, lb + 2048);
}

template <int ACT>
__global__ __launch_bounds__(256) void gemm_bf16(
    const ushort* __restrict__ A, const ushort* __restrict__ B,
    const float* __restrict__ bias, ushort* __restrict__ C,
    int M, int N, int K, float qscale, int qcols, int ntn) {
    __shared__ ushort Abuf[2][128 * 32];
    __shared__ ushort Bbuf[2][32 * 128];

    int nblk = gridDim.x;
    int q = nblk >> 3, rr = nblk & 7;
    int xcd = blockIdx.x & 7, sub = blockIdx.x >> 3;
    int wg = (xcd < rr ? xcd * (q + 1) : rr * (q + 1) + (xcd - rr) * q) + sub;
    int mt = wg / ntn, nt = wg - mt * ntn;
    int m0 = mt * 128, n0 = nt * 128;

    int tid = threadIdx.x;
    int w = tid >> 6, l = tid & 63;
    int wm = w >> 1, wn = w & 1;

    f32x4 acc[4][4];
#pragma unroll
    for (int i = 0; i < 4; ++i)
#pragma unroll
        for (int j = 0; j < 4; ++j)
            acc[i][j] = (f32x4){0.f, 0.f, 0.f, 0.f};

    const int KT = K >> 5;
    gemm_stage(A, B, Abuf[0], Bbuf[0], tid, m0, n0, 0, K, N);
    __syncthreads();
    int cur = 0;
    for (int kt = 0; kt < KT; ++kt) {
        if (kt + 1 < KT)
            gemm_stage(A, B, Abuf[cur ^ 1], Bbuf[cur ^ 1], tid, m0, n0, kt + 1, K, N);
        const char* Ab = (const char*)&Abuf[cur][0];
        const char* Bb = (const char*)&Bbuf[cur][0];
        bf16x8 af[4], bfv[4];
        int kg = l >> 4, c16 = l & 15;
#pragma unroll
        for (int mi = 0; mi < 4; ++mi) {
            int row = wm * 64 + mi * 16 + c16;
            int byt = row * 64 + ((kg ^ ((row >> 1) & 3)) << 4);
            af[mi] = *(const bf16x8*)(Ab + byt);
        }
#pragma unroll
        for (int ni = 0; ni < 4; ++ni) {
            int col = wn * 64 + ni * 16 + c16;
            int byt = kg * 2048 + col * 16;
            bfv[ni] = *(const bf16x8*)(Bb + byt);
        }
#pragma unroll
        for (int mi = 0; mi < 4; ++mi)
#pragma unroll
            for (int ni = 0; ni < 4; ++ni)
                acc[mi][ni] = __builtin_amdgcn_mfma_f32_16x16x32_bf16(
                    af[mi], bfv[ni], acc[mi][ni], 0, 0, 0);
        __syncthreads();
        cur ^= 1;
    }

    int c16 = l & 15, rhi = (l >> 4) * 4;
#pragma unroll
    for (int ni = 0; ni < 4; ++ni) {
        int col = n0 + wn * 64 + ni * 16 + c16;
        float bvv = bias[col];
        bool scl = col < qcols;
#pragma unroll
        for (int mi = 0; mi < 4; ++mi) {
#pragma unroll
            for (int r = 0; r < 4; ++r) {
                int row = m0 + wm * 64 + mi * 16 + rhi + r;
                float v = acc[mi][ni][r] + bvv;
                if (scl) v *= qscale;
                if (ACT == 1) v = 0.5f * v * (1.0f + erff(v * 0.70710678118654752f));
                C[(size_t)row * N + col] = f2bf(v);
            }
        }
    }
}

// ----------------------------- conv0 as implicit GEMM -----------------------
// out[(b,t), o] = relu(BN(sum_kk sum_c hb[b,2t+kk,c] * W[kk][c][o] + cb[o]))
// M = BATCH*37 = 9472 (74 tiles), N = 128, K = 768 per kk, 8 kk passes.
__device__ __forceinline__ void conv0_stage(
    const ushort* __restrict__ hb, const ushort* __restrict__ W,
    ushort* Abuf, ushort* Bbuf, int tid, int m0, int s) {
    int kk = s / 24, kt = s - kk * 24;
    int r0 = tid >> 2;
    int kgrp = (((tid & 3) ^ ((tid >> 3) & 3)) << 3);
    int w = tid >> 6;
    int r = m0 + r0;
    int b1 = r / 37, t1 = r - b1 * 37;
    int tok1 = b1 * SEQL + 2 * t1 + kk;
    int r2 = r + 64;
    int b2 = r2 / 37, t2 = r2 - b2 * 37;
    int tok2 = b2 * SEQL + 2 * t2 + kk;
    const ushort* ga0 = hb + (size_t)tok1 * DMODEL + kt * 32 + kgrp;
    const ushort* ga1 = hb + (size_t)tok2 * DMODEL + kt * 32 + kgrp;
    ushort* la = Abuf + (w * 64) * 8;
    GLL(ga0, la);
    GLL(ga1, la + 2048);
    const ushort* Bk = W + (size_t)kk * 98304;
    int g0 = tid >> 7, nn0 = tid & 127;
    int li1 = 256 + tid;
    int g1 = li1 >> 7, nn1 = li1 & 127;
    ushort* lb = Bbuf + (w * 64) * 8;
    GLL(Bk + ((size_t)(kt * 4 + g0) * 128 + nn0) * 8, lb);
    GLL(Bk + ((size_t)(kt * 4 + g1) * 128 + nn1) * 8, lb + 2048);
}

__global__ __launch_bounds__(256) void conv0_gemm(
    const ushort* __restrict__ hb, const ushort* __restrict__ W,
    const float* __restrict__ cb, const float* __restrict__ g,
    const float* __restrict__ bb, const float* __restrict__ bm,
    const float* __restrict__ bv, float* __restrict__ out) {
    __shared__ ushort Abuf[2][128 * 32];
    __shared__ ushort Bbuf[2][32 * 128];
    int m0 = blockIdx.x * 128;
    int tid = threadIdx.x;
    int w = tid >> 6, l = tid & 63;
    int wm = w >> 1, wn = w & 1;
    f32x4 acc[4][4];
#pragma unroll
    for (int i = 0; i < 4; ++i)
#pragma unroll
        for (int j = 0; j < 4; ++j)
            acc[i][j] = (f32x4){0.f, 0.f, 0.f, 0.f};

    conv0_stage(hb, W, Abuf[0], Bbuf[0], tid, m0, 0);
    __syncthreads();
    int cur = 0;
    for (int s = 0; s < 192; ++s) {
        if (s + 1 < 192)
            conv0_stage(hb, W, Abuf[cur ^ 1], Bbuf[cur ^ 1], tid, m0, s + 1);
        const char* Ab = (const char*)&Abuf[cur][0];
        const char* Bb = (const char*)&Bbuf[cur][0];
        bf16x8 af[4], bfv[4];
        int kg = l >> 4, c16 = l & 15;
#pragma unroll
        for (int mi = 0; mi < 4; ++mi) {
            int row = wm * 64 + mi * 16 + c16;
            int byt = row * 64 + ((kg ^ ((row >> 1) & 3)) << 4);
            af[mi] = *(const bf16x8*)(Ab + byt);
        }
#pragma unroll
        for (int ni = 0; ni < 4; ++ni) {
            int col = wn * 64 + ni * 16 + c16;
            int byt = kg * 2048 + col * 16;
            bfv[ni] = *(const bf16x8*)(Bb + byt);
        }
#pragma unroll
        for (int mi = 0; mi < 4; ++mi)
#pragma unroll
            for (int ni = 0; ni < 4; ++ni)
                acc[mi][ni] = __builtin_amdgcn_mfma_f32_16x16x32_bf16(
                    af[mi], bfv[ni], acc[mi][ni], 0, 0, 0);
        __syncthreads();
        cur ^= 1;
    }

    int c16 = l & 15, rhi = (l >> 4) * 4;
#pragma unroll
    for (int ni = 0; ni < 4; ++ni) {
        int col = wn * 64 + ni * 16 + c16;  // output channel o
        float scl = g[col] * rsqrtf(bv[col] + 1e-5f);
        float cbv = cb[col];
        float shl = bb[col] - bm[col] * scl;
#pragma unroll
        for (int mi = 0; mi < 4; ++mi) {
#pragma unroll
            for (int r = 0; r < 4; ++r) {
                int row = m0 + wm * 64 + mi * 16 + rhi + r;
                int b = row / 37, t = row - b * 37;
                float v = (acc[mi][ni][r] + cbv) * scl + shl;
                out[(size_t)b * (128 * 37) + col * 37 + t] = fmaxf(v, 0.f);
            }
        }
    }
}

// ----------------------------- fused attention -----------------------------
// qkv: [tok][2304] bf16 (q|k|v); one block (4 waves) per (b,h)
__global__ __launch_bounds__(256) void attn_kernel(
    const ushort* __restrict__ qkv, ushort* __restrict__ o) {
    __shared__ float kst[64][91];
    __shared__ float vs[SEQL][64];
    int b = blockIdx.x / NH, h = blockIdx.x % NH;
    size_t base = (size_t)b * SEQL * 2304 + h * HD;
    for (int idx = threadIdx.x; idx < SEQL * HD; idx += 256) {
        int s = idx >> 6, d = idx & 63;
        kst[d][s] = bf2f(qkv[base + 768 + (size_t)s * 2304 + d]);
        vs[s][d] = bf2f(qkv[base + 1536 + (size_t)s * 2304 + d]);
    }
    __syncthreads();
    int w = threadIdx.x >> 6, l = threadIdx.x & 63;
    bool has2 = (l < SEQL - 64);
    int j2 = has2 ? 64 + l : 80;
    for (int r = w; r < SEQL; r += 4) {
        float qd = bf2f(qkv[base + (size_t)r * 2304 + l]);
        float s0 = 0.f, s1 = 0.f;
#pragma unroll 8
        for (int d = 0; d < 64; ++d) {
            float qv = __shfl(qd, d, 64);
            s0 += qv * kst[d][l];
            s1 += qv * kst[d][j2];
        }
        if (!has2) s1 = -1e30f;
        float mx = wave_max(fmaxf(s0, s1));
        float p0 = expf(s0 - mx);
        float p1 = has2 ? expf(s1 - mx) : 0.f;
        float inv = 1.0f / wave_sum_x(p0 + p1);
        p0 *= inv; p1 *= inv;
        float acc = 0.f;
#pragma unroll 8
        for (int j = 0; j < 64; ++j)
            acc += __shfl(p0, j, 64) * vs[j][l];
#pragma unroll
        for (int j = 64; j < SEQL; ++j)
            acc += __shfl(p1, j - 64, 64) * vs[j][l];
        int tok = b * SEQL + r;
        o[(size_t)tok * DMODEL + h * HD + l] = f2bf(acc);
    }
}

// ----------------------------- small conv tail -----------------------------
__global__ void conv1_kernel(const float* __restrict__ x, const float* __restrict__ w,
                             const float* __restrict__ cb, const float* __restrict__ g,
                             const float* __restrict__ bb, const float* __restrict__ bm,
                             const float* __restrict__ bv, float* __restrict__ out) {
    int idx = blockIdx.x * blockDim.x + threadIdx.x;
    if (idx >= BATCH * 64 * 14) return;
    int t = idx % 14, o = (idx / 14) % 64, b = idx / (14 * 64);
    float acc = cb[o];
    const float* wo = w + (long)o * 128 * 8;
    const float* xb = x + (long)b * 128 * 35;
    for (int c = 0; c < 128; ++c) {
#pragma unroll
        for (int kk = 0; kk < 8; ++kk)
            acc += xb[c * 35 + 2 * t + kk] * wo[c * 8 + kk];
    }
    float y = (acc - bm[o]) * g[o] * rsqrtf(bv[o] + 1e-5f) + bb[o];
    out[idx] = fmaxf(y, 0.0f);
}

__global__ void conv2_kernel(const float* __restrict__ x, const float* __restrict__ w,
                             const float* __restrict__ cb, const float* __restrict__ g,
                             const float* __restrict__ bb, const float* __restrict__ bm,
                             const float* __restrict__ bv, float* __restrict__ out) {
    int idx = blockIdx.x * blockDim.x + threadIdx.x;
    if (idx >= BATCH * 32 * 5) return;
    int t = idx % 5, o = (idx / 5) % 32, b = idx / (5 * 32);
    float acc = cb[o];
    const float* wo = w + (long)o * 64 * 3;
    const float* xb = x + (long)b * 64 * 12;
    for (int c = 0; c < 64; ++c) {
#pragma unroll
        for (int kk = 0; kk < 3; ++kk)
            acc += xb[c * 12 + 2 * t + kk] * wo[c * 3 + kk];
    }
    float y = (acc - bm[o]) * g[o] * rsqrtf(bv[o] + 1e-5f) + bb[o];
    out[idx] = fmaxf(y, 0.0f);
}

__global__ void pool_kernel(const float* __restrict__ in, float* __restrict__ out,
                            int C, int Tin) {
    int Tout = Tin - 2;
    int idx = blockIdx.x * blockDim.x + threadIdx.x;
    if (idx >= BATCH * C * Tout) return;
    int t = idx % Tout;
    int co = idx / Tout;
    const float* p = in + (long)co * Tin + t;
    out[idx] = fmaxf(fmaxf(p[0], p[1]), p[2]);
}

__global__ __launch_bounds__(64) void head_kernel(
    const float* __restrict__ x, const float* __restrict__ w1,
    const float* __restrict__ b1, const float* __restrict__ w2,
    const float* __restrict__ b2, float* __restrict__ out) {
    int b = blockIdx.x;
    int j = threadIdx.x;
    float y = 0.f;
    if (j < 32) {
        float acc = b1[j];
        const float* xb = x + b * 96;
        for (int i = 0; i < 96; ++i) acc += xb[i] * w1[j * 96 + i];
        y = fmaxf(acc, 0.0f) * w2[j];
    }
#pragma unroll
    for (int o = 32; o > 0; o >>= 1) y += __shfl_down(y, o, 64);
    if (j == 0) out[b] = 1.0f / (1.0f + expf(-(y + b2[0])));
}

// ----------------------------- launch -----------------------------
extern "C" void kernel_launch(void* const* d_in, const int* in_sizes, int n_in,
                              void* d_out, int out_size, void* d_ws, size_t ws_size,
                              hipStream_t stream) {
    const int*   ids  = (const int*)d_in[0];
    const float* wemb = (const float*)d_in[1];
    const float* pemb = (const float*)d_in[2];
    const float* elng = (const float*)d_in[3];
    const float* elnb = (const float*)d_in[4];
    const float* wq = (const float*)d_in[5];
    const float* bq = (const float*)d_in[6];
    const float* wk = (const float*)d_in[7];
    const float* bk = (const float*)d_in[8];
    const float* wv = (const float*)d_in[9];
    const float* bv = (const float*)d_in[10];
    const float* wo = (const float*)d_in[11];
    const float* bo = (const float*)d_in[12];
    const float* ln1g = (const float*)d_in[13];
    const float* ln1b = (const float*)d_in[14];
    const float* w1 = (const float*)d_in[15];
    const float* b1 = (const float*)d_in[16];
    const float* w2 = (const float*)d_in[17];
    const float* b2 = (const float*)d_in[18];
    const float* ln2g = (const float*)d_in[19];
    const float* ln2b = (const float*)d_in[20];
    const float* c0w = (const float*)d_in[21];
    const float* c0b = (const float*)d_in[22];
    const float* g0 = (const float*)d_in[23];
    const float* bb0 = (const float*)d_in[24];
    const float* m0 = (const float*)d_in[25];
    const float* v0 = (const float*)d_in[26];
    const float* c1w = (const float*)d_in[27];
    const float* c1b = (const float*)d_in[28];
    const float* g1 = (const float*)d_in[29];
    const float* bb1 = (const float*)d_in[30];
    const float* m1 = (const float*)d_in[31];
    const float* v1 = (const float*)d_in[32];
    const float* c2w = (const float*)d_in[33];
    const float* c2b = (const float*)d_in[34];
    const float* g2 = (const float*)d_in[35];
    const float* bb2 = (const float*)d_in[36];
    const float* m2 = (const float*)d_in[37];
    const float* v2 = (const float*)d_in[38];
    const float* d1w = (const float*)d_in[39];
    const float* d1b = (const float*)d_in[40];
    const float* d2w = (const float*)d_in[41];
    const float* d2b = (const float*)d_in[42];
    (void)in_sizes; (void)n_in; (void)out_size;

    const size_t SZ = (size_t)NTOK * DMODEL;
    char* p = (char*)d_ws;
    float*  h    = (float*)p;  p += SZ * 4;
    ushort* hb   = (ushort*)p; p += SZ * 2;
    ushort* qkvb = (ushort*)p; p += (size_t)NTOK * 2304 * 2;
    ushort* ob   = (ushort*)p; p += SZ * 2;
    ushort* rb   = (ushort*)p; p += SZ * 2;
    ushort* qkvw = (ushort*)p; p += (size_t)DMODEL * 2304 * 2;
    ushort* wob  = (ushort*)p; p += (size_t)DMODEL * DMODEL * 2;
    ushort* w1b  = (ushort*)p; p += (size_t)DMODEL * FFDIM * 2;
    ushort* w2b  = (ushort*)p; p += (size_t)FFDIM * DMODEL * 2;
    float*  cbias= (float*)p;  p += 2304 * 4;
    ushort* wc0  = (ushort*)p; p += (size_t)8 * 96 * 128 * 8 * 2;
    float* c0 = (float*)p;  p += (size_t)BATCH * 128 * 37 * 4;
    float* p0 = (float*)p;  p += (size_t)BATCH * 128 * 35 * 4;
    float* c1 = (float*)p;  p += (size_t)BATCH * 64 * 14 * 4;
    float* p1 = (float*)p;  p += (size_t)BATCH * 64 * 12 * 4;
    float* c2 = (float*)p;  p += (size_t)BATCH * 32 * 5 * 4;
    float* p2 = (float*)p;  p += (size_t)BATCH * 32 * 3 * 4;
    ushort* ff = (ushort*)p;
    size_t used = (size_t)(p - (char*)d_ws);
    bool full = (used + (size_t)NTOK * FFDIM * 2) <= ws_size;
    const int FCH = full ? NTOK : FFCH;
    const int nch = full ? 1 : 3;

    embed_ln_kernel<<<NTOK, 256, 0, stream>>>(ids, wemb, pemb, elng, elnb, h, hb);
    convw_c0<<<(128 * 768 * 8 + 255) / 256, 256, 0, stream>>>(c0w, wc0);

    const int NWG_QKV = (NTOK / 128) * (2304 / 128);   // 162*18 = 2916
    const int NWG_WO  = (NTOK / 128) * (DMODEL / 128); // 162*6  = 972
    const int NWG_F1  = (FCH / 128) * (FFDIM / 128);
    const int NWG_F2  = (FCH / 128) * (DMODEL / 128);

    for (int l = 0; l < NLAYER; ++l) {
        convw_layer<<<4096, 256, 0, stream>>>(
            wq + (size_t)l * SQ1, wk + (size_t)l * SQ1, wv + (size_t)l * SQ1,
            wo + (size_t)l * SQ1, w1 + (size_t)l * SQ2, w2 + (size_t)l * SQ2,
            bq + (size_t)l * DMODEL, bk + (size_t)l * DMODEL, bv + (size_t)l * DMODEL,
            qkvw, wob, w1b, w2b, cbias);

        gemm_bf16<0><<<NWG_QKV, 256, 0, stream>>>(hb, qkvw, cbias, qkvb,
                                                  NTOK, 2304, DMODEL, 0.125f, 768, 18);
        attn_kernel<<<BATCH * NH, 256, 0, stream>>>(qkvb, ob);
        gemm_bf16<0><<<NWG_WO, 256, 0, stream>>>(ob, wob, bo + (size_t)l * DMODEL, rb,
                                                 NTOK, DMODEL, DMODEL, 1.0f, 0, 6);
        add_ln_kernel<<<NTOK, 192, 0, stream>>>(h, rb, ln1g + (size_t)l * DMODEL,
                                                ln1b + (size_t)l * DMODEL, hb);
        for (int ch = 0; ch < nch; ++ch) {
            const ushort* hc = hb + (size_t)ch * FCH * DMODEL;
            ushort* rc = rb + (size_t)ch * FCH * DMODEL;
            gemm_bf16<1><<<NWG_F1, 256, 0, stream>>>(hc, w1b, b1 + (size_t)l * FFDIM, ff,
                                                     FCH, FFDIM, DMODEL, 1.0f, 0, FFDIM / 128);
            gemm_bf16<0><<<NWG_F2, 256, 0, stream>>>(ff, w2b, b2 + (size_t)l * DMODEL, rc,
                                                     FCH, DMODEL, FFDIM, 1.0f, 0, DMODEL / 128);
        }
        add_ln_kernel<<<NTOK, 192, 0, stream>>>(h, rb, ln2g + (size_t)l * DMODEL,
                                                ln2b + (size_t)l * DMODEL, hb);
    }

    // CNN / MLP head
    {
        conv0_gemm<<<74, 256, 0, stream>>>(hb, wc0, c0b, g0, bb0, m0, v0, c0);
        int n = BATCH * 128 * 35;
        pool_kernel<<<(n + 255) / 256, 256, 0, stream>>>(c0, p0, 128, 37);
        n = BATCH * 64 * 14;
        conv1_kernel<<<(n + 255) / 256, 256, 0, stream>>>(p0, c1w, c1b, g1, bb1, m1, v1, c1);
        n = BATCH * 64 * 12;
        pool_kernel<<<(n + 255) / 256, 256, 0, stream>>>(c1, p1, 64, 14);
        n = BATCH * 32 * 5;
        conv2_kernel<<<(n + 255) / 256, 256, 0, stream>>>(p1, c2w, c2b, g2, bb2, m2, v2, c2);
        n = BATCH * 32 * 3;
        pool_kernel<<<(n + 255) / 256, 256, 0, stream>>>(c2, p2, 32, 5);
        head_kernel<<<BATCH, 64, 0, stream>>>(p2, d1w, d1b, d2w, d2b, (float*)d_out);
    }
}

// Round 4
// 7206.094 us; speedup vs baseline: 9.2791x; 1.8404x over previous
//
#include <hip/hip_runtime.h>
#include <hip/hip_bf16.h>

#define DMODEL 768
#define HD     64
#define NH     12
#define SEQL   81
#define BATCH  256
#define NTOK   (BATCH*SEQL)   /* 20736 */
#define FFDIM  3072
#define NLAYER 12
#define FFCH   6912           /* fallback FFN row chunk */

typedef __bf16 bf16x8 __attribute__((ext_vector_type(8)));
typedef float  f32x4  __attribute__((ext_vector_type(4)));
typedef unsigned short us8 __attribute__((ext_vector_type(8)));

__device__ __forceinline__ float bf2f(ushort u) {
    union { float f; unsigned u; } c; c.u = ((unsigned)u) << 16; return c.f;
}
__device__ __forceinline__ ushort f2bf(float f) {
    union { float f; unsigned u; } c; c.f = f;
    unsigned x = c.u;
    unsigned r = (x + 0x7fffu + ((x >> 16) & 1u)) >> 16;
    return (ushort)r;
}

#define GLL(gptr, lptr) __builtin_amdgcn_global_load_lds( \
    (const __attribute__((address_space(1))) void*)(gptr), \
    (__attribute__((address_space(3))) void*)(lptr), 16, 0, 0)

// ----------------------------- reductions -----------------------------
__device__ __forceinline__ float wave_sum(float v) {
#pragma unroll
    for (int o = 32; o > 0; o >>= 1) v += __shfl_down(v, o, 64);
    return v;
}

__device__ __forceinline__ void block_sum2_w4(float& a, float& b, float* red) {
    a = wave_sum(a); b = wave_sum(b);
    int lane = threadIdx.x & 63, wid = threadIdx.x >> 6;
    if (lane == 0) { red[wid] = a; red[4 + wid] = b; }
    __syncthreads();
    a = red[0] + red[1] + red[2] + red[3];
    b = red[4] + red[5] + red[6] + red[7];
    __syncthreads();
}
__device__ __forceinline__ void block_sum2_w3(float& a, float& b, float* red) {
    a = wave_sum(a); b = wave_sum(b);
    int lane = threadIdx.x & 63, wid = threadIdx.x >> 6;
    if (lane == 0) { red[wid] = a; red[3 + wid] = b; }
    __syncthreads();
    a = red[0] + red[1] + red[2];
    b = red[3] + red[4] + red[5];
    __syncthreads();
}

// ----------------------------- embedding + LN -----------------------------
__global__ __launch_bounds__(256) void embed_ln_kernel(
    const int* __restrict__ ids, const float* __restrict__ wemb,
    const float* __restrict__ pemb, const float* __restrict__ g,
    const float* __restrict__ b, float* __restrict__ out,
    ushort* __restrict__ outb) {
    __shared__ float red[8];
    int tok = blockIdx.x;
    int s = tok % SEQL;
    long base = (long)ids[tok] * DMODEL;
    float vals[3];
    float sum = 0.f, sq = 0.f;
#pragma unroll
    for (int i = 0; i < 3; ++i) {
        int c = threadIdx.x + i * 256;
        float x = wemb[base + c] + pemb[s * DMODEL + c];
        vals[i] = x; sum += x; sq += x * x;
    }
    block_sum2_w4(sum, sq, red);
    float mean = sum * (1.0f / DMODEL);
    float inv = rsqrtf(sq * (1.0f / DMODEL) - mean * mean + 1e-5f);
#pragma unroll
    for (int i = 0; i < 3; ++i) {
        int c = threadIdx.x + i * 256;
        float y = (vals[i] - mean) * inv * g[c] + b[c];
        out[(size_t)tok * DMODEL + c] = y;
        outb[(size_t)tok * DMODEL + c] = f2bf(y);
    }
}

// h = LN(h + r); writes fp32 h and plain bf16 hb. 192 threads, float4.
__global__ __launch_bounds__(192) void add_ln_kernel(
    float* __restrict__ h, const ushort* __restrict__ r,
    const float* __restrict__ g, const float* __restrict__ b,
    ushort* __restrict__ hb) {
    __shared__ float red[6];
    size_t base = (size_t)blockIdx.x * DMODEL;
    int c = threadIdx.x * 4;
    float4 hv = *(const float4*)(h + base + c);
    ushort4 rv = *(const ushort4*)(r + base + c);
    float vals[4];
    vals[0] = hv.x + bf2f(rv.x); vals[1] = hv.y + bf2f(rv.y);
    vals[2] = hv.z + bf2f(rv.z); vals[3] = hv.w + bf2f(rv.w);
    float sum = 0.f, sq = 0.f;
#pragma unroll
    for (int i = 0; i < 4; ++i) { sum += vals[i]; sq += vals[i] * vals[i]; }
    block_sum2_w3(sum, sq, red);
    float mean = sum * (1.0f / DMODEL);
    float inv = rsqrtf(sq * (1.0f / DMODEL) - mean * mean + 1e-5f);
    float4 gv = *(const float4*)(g + c);
    float4 bv = *(const float4*)(b + c);
    float y0 = (vals[0] - mean) * inv * gv.x + bv.x;
    float y1 = (vals[1] - mean) * inv * gv.y + bv.y;
    float y2 = (vals[2] - mean) * inv * gv.z + bv.z;
    float y3 = (vals[3] - mean) * inv * gv.w + bv.w;
    *(float4*)(h + base + c) = make_float4(y0, y1, y2, y3);
    ushort4 ov; ov.x = f2bf(y0); ov.y = f2bf(y1); ov.z = f2bf(y2); ov.w = f2bf(y3);
    *(ushort4*)(hb + base + c) = ov;
}

// ----------------------------- weight conversion (per layer, fused) -----------
#define SQ1 589824                 /* 768*768 */
#define SQ2 2359296                /* 768*3072 */
#define CW_TOTAL (4*SQ1 + 2*SQ2 + 2304)
__global__ __launch_bounds__(256) void convw_layer(
    const float* __restrict__ wq, const float* __restrict__ wk,
    const float* __restrict__ wv, const float* __restrict__ wo,
    const float* __restrict__ w1, const float* __restrict__ w2,
    const float* __restrict__ bq, const float* __restrict__ bk,
    const float* __restrict__ bvp,
    ushort* __restrict__ qkvw, ushort* __restrict__ wob,
    ushort* __restrict__ w1b, ushort* __restrict__ w2b,
    float* __restrict__ cbias) {
    for (int i = blockIdx.x * 256 + threadIdx.x; i < CW_TOTAL; i += gridDim.x * 256) {
        if (i < 3 * SQ1) {
            int widx = i / SQ1, j = i - widx * SQ1;
            const float* src = widx == 0 ? wq : (widx == 1 ? wk : wv);
            int k = j / 768, n = j - k * 768;
            qkvw[(size_t)(k >> 3) * 2304 * 8 + (widx * 768 + n) * 8 + (k & 7)] = f2bf(src[j]);
        } else if (i < 4 * SQ1) {
            int j = i - 3 * SQ1;
            int k = j / 768, n = j - k * 768;
            wob[(size_t)(k >> 3) * 768 * 8 + n * 8 + (k & 7)] = f2bf(wo[j]);
        } else if (i < 4 * SQ1 + SQ2) {
            int j = i - 4 * SQ1;
            int k = j / 3072, n = j - k * 3072;
            w1b[(size_t)(k >> 3) * 3072 * 8 + n * 8 + (k & 7)] = f2bf(w1[j]);
        } else if (i < 4 * SQ1 + 2 * SQ2) {
            int j = i - 4 * SQ1 - SQ2;
            int k = j / 768, n = j - k * 768;
            w2b[(size_t)(k >> 3) * 768 * 8 + n * 8 + (k & 7)] = f2bf(w2[j]);
        } else {
            int j = i - 4 * SQ1 - 2 * SQ2;
            cbias[j] = j < 768 ? bq[j] : (j < 1536 ? bk[j - 768] : bvp[j - 1536]);
        }
    }
}

// conv0 weights: w[o][c][kk] fp32 -> dst[kk][(c>>3)*1024 + o*8 + (c&7)] bf16
__global__ __launch_bounds__(256) void convw_c0(
    const float* __restrict__ w, ushort* __restrict__ dst) {
    int idx = blockIdx.x * 256 + threadIdx.x;
    if (idx >= 128 * 768 * 8) return;
    int o = idx / 6144, rem = idx - o * 6144, c = rem >> 3, kk = rem & 7;
    dst[(size_t)kk * 98304 + (size_t)(c >> 3) * 1024 + o * 8 + (c & 7)] = f2bf(w[idx]);
}

// ----------------------------- bf16 MFMA GEMM -----------------------------
__device__ __forceinline__ void gemm_stage(
    const ushort* __restrict__ A, const ushort* __restrict__ B,
    ushort* Abuf, ushort* Bbuf, int tid,
    int m0, int n0, int kt, int K, int N) {
    int r0 = tid >> 2;
    int kgrp = (((tid & 3) ^ ((tid >> 3) & 3)) << 3);
    const ushort* ga0 = A + (size_t)(m0 + r0) * K + kt * 32 + kgrp;
    int w = tid >> 6;
    ushort* la = Abuf + (w * 64) * 8;
    GLL(ga0, la);
    GLL(ga0 + (size_t)64 * K, la + 2048);
    int g0 = tid >> 7, nn0 = tid & 127;
    const ushort* gb0 = B + ((size_t)(kt * 4 + g0) * N + n0 + nn0) * 8;
    int li1 = 256 + tid;
    int g1 = li1 >> 7, nn1 = li1 & 127;
    const ushort* gb1 = B + ((size_t)(kt * 4 + g1) * N + n0 + nn1) * 8;
    ushort* lb = Bbuf + (w * 64) * 8;
    GLL(gb0, lb);
    GLL(gb1, lb + 2048);
}

template <int ACT>
__global__ __launch_bounds__(256) void gemm_bf16(
    const ushort* __restrict__ A, const ushort* __restrict__ B,
    const float* __restrict__ bias, ushort* __restrict__ C,
    int M, int N, int K, float qscale, int qcols, int ntn) {
    __shared__ ushort Abuf[2][128 * 32];
    __shared__ ushort Bbuf[2][32 * 128];

    int nblk = gridDim.x;
    int q = nblk >> 3, rr = nblk & 7;
    int xcd = blockIdx.x & 7, sub = blockIdx.x >> 3;
    int wg = (xcd < rr ? xcd * (q + 1) : rr * (q + 1) + (xcd - rr) * q) + sub;
    int mt = wg / ntn, nt = wg - mt * ntn;
    int m0 = mt * 128, n0 = nt * 128;

    int tid = threadIdx.x;
    int w = tid >> 6, l = tid & 63;
    int wm = w >> 1, wn = w & 1;

    f32x4 acc[4][4];
#pragma unroll
    for (int i = 0; i < 4; ++i)
#pragma unroll
        for (int j = 0; j < 4; ++j)
            acc[i][j] = (f32x4){0.f, 0.f, 0.f, 0.f};

    const int KT = K >> 5;
    gemm_stage(A, B, Abuf[0], Bbuf[0], tid, m0, n0, 0, K, N);
    __syncthreads();
    int cur = 0;
    for (int kt = 0; kt < KT; ++kt) {
        if (kt + 1 < KT)
            gemm_stage(A, B, Abuf[cur ^ 1], Bbuf[cur ^ 1], tid, m0, n0, kt + 1, K, N);
        const char* Ab = (const char*)&Abuf[cur][0];
        const char* Bb = (const char*)&Bbuf[cur][0];
        bf16x8 af[4], bfv[4];
        int kg = l >> 4, c16 = l & 15;
#pragma unroll
        for (int mi = 0; mi < 4; ++mi) {
            int row = wm * 64 + mi * 16 + c16;
            int byt = row * 64 + ((kg ^ ((row >> 1) & 3)) << 4);
            af[mi] = *(const bf16x8*)(Ab + byt);
        }
#pragma unroll
        for (int ni = 0; ni < 4; ++ni) {
            int col = wn * 64 + ni * 16 + c16;
            int byt = kg * 2048 + col * 16;
            bfv[ni] = *(const bf16x8*)(Bb + byt);
        }
#pragma unroll
        for (int mi = 0; mi < 4; ++mi)
#pragma unroll
            for (int ni = 0; ni < 4; ++ni)
                acc[mi][ni] = __builtin_amdgcn_mfma_f32_16x16x32_bf16(
                    af[mi], bfv[ni], acc[mi][ni], 0, 0, 0);
        __syncthreads();
        cur ^= 1;
    }

    int c16 = l & 15, rhi = (l >> 4) * 4;
#pragma unroll
    for (int ni = 0; ni < 4; ++ni) {
        int col = n0 + wn * 64 + ni * 16 + c16;
        float bvv = bias[col];
        bool scl = col < qcols;
#pragma unroll
        for (int mi = 0; mi < 4; ++mi) {
#pragma unroll
            for (int r = 0; r < 4; ++r) {
                int row = m0 + wm * 64 + mi * 16 + rhi + r;
                float v = acc[mi][ni][r] + bvv;
                if (scl) v *= qscale;
                if (ACT == 1) v = 0.5f * v * (1.0f + erff(v * 0.70710678118654752f));
                C[(size_t)row * N + col] = f2bf(v);
            }
        }
    }
}

// ----------------------------- conv0 as implicit GEMM -----------------------
__device__ __forceinline__ void conv0_stage(
    const ushort* __restrict__ hb, const ushort* __restrict__ W,
    ushort* Abuf, ushort* Bbuf, int tid, int m0, int s) {
    int kk = s / 24, kt = s - kk * 24;
    int r0 = tid >> 2;
    int kgrp = (((tid & 3) ^ ((tid >> 3) & 3)) << 3);
    int w = tid >> 6;
    int r = m0 + r0;
    int b1 = r / 37, t1 = r - b1 * 37;
    int tok1 = b1 * SEQL + 2 * t1 + kk;
    int r2 = r + 64;
    int b2 = r2 / 37, t2 = r2 - b2 * 37;
    int tok2 = b2 * SEQL + 2 * t2 + kk;
    const ushort* ga0 = hb + (size_t)tok1 * DMODEL + kt * 32 + kgrp;
    const ushort* ga1 = hb + (size_t)tok2 * DMODEL + kt * 32 + kgrp;
    ushort* la = Abuf + (w * 64) * 8;
    GLL(ga0, la);
    GLL(ga1, la + 2048);
    const ushort* Bk = W + (size_t)kk * 98304;
    int g0 = tid >> 7, nn0 = tid & 127;
    int li1 = 256 + tid;
    int g1 = li1 >> 7, nn1 = li1 & 127;
    ushort* lb = Bbuf + (w * 64) * 8;
    GLL(Bk + ((size_t)(kt * 4 + g0) * 128 + nn0) * 8, lb);
    GLL(Bk + ((size_t)(kt * 4 + g1) * 128 + nn1) * 8, lb + 2048);
}

__global__ __launch_bounds__(256) void conv0_gemm(
    const ushort* __restrict__ hb, const ushort* __restrict__ W,
    const float* __restrict__ cb, const float* __restrict__ g,
    const float* __restrict__ bb, const float* __restrict__ bm,
    const float* __restrict__ bv, float* __restrict__ out) {
    __shared__ ushort Abuf[2][128 * 32];
    __shared__ ushort Bbuf[2][32 * 128];
    int m0 = blockIdx.x * 128;
    int tid = threadIdx.x;
    int w = tid >> 6, l = tid & 63;
    int wm = w >> 1, wn = w & 1;
    f32x4 acc[4][4];
#pragma unroll
    for (int i = 0; i < 4; ++i)
#pragma unroll
        for (int j = 0; j < 4; ++j)
            acc[i][j] = (f32x4){0.f, 0.f, 0.f, 0.f};

    conv0_stage(hb, W, Abuf[0], Bbuf[0], tid, m0, 0);
    __syncthreads();
    int cur = 0;
    for (int s = 0; s < 192; ++s) {
        if (s + 1 < 192)
            conv0_stage(hb, W, Abuf[cur ^ 1], Bbuf[cur ^ 1], tid, m0, s + 1);
        const char* Ab = (const char*)&Abuf[cur][0];
        const char* Bb = (const char*)&Bbuf[cur][0];
        bf16x8 af[4], bfv[4];
        int kg = l >> 4, c16 = l & 15;
#pragma unroll
        for (int mi = 0; mi < 4; ++mi) {
            int row = wm * 64 + mi * 16 + c16;
            int byt = row * 64 + ((kg ^ ((row >> 1) & 3)) << 4);
            af[mi] = *(const bf16x8*)(Ab + byt);
        }
#pragma unroll
        for (int ni = 0; ni < 4; ++ni) {
            int col = wn * 64 + ni * 16 + c16;
            int byt = kg * 2048 + col * 16;
            bfv[ni] = *(const bf16x8*)(Bb + byt);
        }
#pragma unroll
        for (int mi = 0; mi < 4; ++mi)
#pragma unroll
            for (int ni = 0; ni < 4; ++ni)
                acc[mi][ni] = __builtin_amdgcn_mfma_f32_16x16x32_bf16(
                    af[mi], bfv[ni], acc[mi][ni], 0, 0, 0);
        __syncthreads();
        cur ^= 1;
    }

    int c16 = l & 15, rhi = (l >> 4) * 4;
#pragma unroll
    for (int ni = 0; ni < 4; ++ni) {
        int col = wn * 64 + ni * 16 + c16;
        float scl = g[col] * rsqrtf(bv[col] + 1e-5f);
        float cbv = cb[col];
        float shl = bb[col] - bm[col] * scl;
#pragma unroll
        for (int mi = 0; mi < 4; ++mi) {
#pragma unroll
            for (int r = 0; r < 4; ++r) {
                int row = m0 + wm * 64 + mi * 16 + rhi + r;
                int b = row / 37, t = row - b * 37;
                float v = (acc[mi][ni][r] + cbv) * scl + shl;
                out[(size_t)b * (128 * 37) + col * 37 + t] = fmaxf(v, 0.f);
            }
        }
    }
}

// ----------------------------- MFMA fused attention -------------------------
// one block (4 waves, 2x2) per (b,h); S padded 81->96; qkv: [tok][2304] bf16.
__global__ __launch_bounds__(256) void attn_mfma(
    const ushort* __restrict__ qkv, ushort* __restrict__ o) {
    __shared__ ushort Qs[96 * 64];        // [row][64] chunk-swizzled (^row&7)
    __shared__ ushort Ks[96 * 64];        // same
    __shared__ ushort Vs[12 * 64 * 8];    // B-layout [kgrp][d][8]
    __shared__ ushort Ps[96 * 128];       // [row][128] chunk-swizzled (^row&7)
    __shared__ float pmax[2][96];
    __shared__ float psum[2][96];

    int b = blockIdx.x / NH, h = blockIdx.x % NH;
    const ushort* qp = qkv + (size_t)b * SEQL * 2304 + h * HD;
    const ushort* kp = qp + 768;
    const ushort* vp = qp + 1536;

    int tid = threadIdx.x;
    int w = tid >> 6, l = tid & 63;
    int wm = w >> 1, wn = w & 1;
    int kg = l >> 4, c16 = l & 15;

    // stage Q,K via global_load_lds with pre-swizzled per-lane source
    {
        int lrow = l >> 3, chunk = l & 7;
#pragma unroll
        for (int p = 0; p < 3; ++p) {
            int seg = p * 4 + w;
            int row = seg * 8 + lrow;
            int rowg = row < SEQL ? row : SEQL - 1;
            int sch = chunk ^ (row & 7);
            GLL(qp + (size_t)rowg * 2304 + sch * 8, Qs + seg * 512);
            GLL(kp + (size_t)rowg * 2304 + sch * 8, Ks + seg * 512);
        }
    }
    // stage V into B-layout (reg-staged scatter; keys clamped -> finite)
#pragma unroll
    for (int p = 0; p < 3; ++p) {
        int t = p * 256 + tid;
        int key = t >> 3, dg = t & 7;
        int keyg = key < SEQL ? key : SEQL - 1;
        us8 vv = *(const us8*)(vp + (size_t)keyg * 2304 + dg * 8);
        int base = (key >> 3) * 512 + dg * 64 + (key & 7);
#pragma unroll
        for (int j = 0; j < 8; ++j) Vs[base + j * 8] = vv[j];
    }
    __syncthreads();

    // ---- QK^T: wave (wm,wn) owns rows wm*48+48, cols wn*48+48 ----
    f32x4 sacc[3][3];
#pragma unroll
    for (int i = 0; i < 3; ++i)
#pragma unroll
        for (int j = 0; j < 3; ++j) sacc[i][j] = (f32x4){0.f, 0.f, 0.f, 0.f};
    {
        const char* Qc = (const char*)Qs;
        const char* Kc = (const char*)Ks;
#pragma unroll
        for (int kt = 0; kt < 2; ++kt) {
            bf16x8 qa[3], ka[3];
#pragma unroll
            for (int mi = 0; mi < 3; ++mi) {
                int row = wm * 48 + mi * 16 + c16;
                qa[mi] = *(const bf16x8*)(Qc + row * 128 + (((kt * 4 + kg) ^ (row & 7)) << 4));
            }
#pragma unroll
            for (int ni = 0; ni < 3; ++ni) {
                int col = wn * 48 + ni * 16 + c16;
                ka[ni] = *(const bf16x8*)(Kc + col * 128 + (((kt * 4 + kg) ^ (col & 7)) << 4));
            }
#pragma unroll
            for (int mi = 0; mi < 3; ++mi)
#pragma unroll
                for (int ni = 0; ni < 3; ++ni)
                    sacc[mi][ni] = __builtin_amdgcn_mfma_f32_16x16x32_bf16(
                        qa[mi], ka[ni], sacc[mi][ni], 0, 0, 0);
        }
    }

    // ---- softmax (deferred normalization): rowmax ----
#pragma unroll
    for (int mi = 0; mi < 3; ++mi) {
#pragma unroll
        for (int r = 0; r < 4; ++r) {
            float m = -3e30f;
#pragma unroll
            for (int ni = 0; ni < 3; ++ni) {
                int col = wn * 48 + ni * 16 + c16;
                float v = sacc[mi][ni][r];
                if (col >= SEQL) { v = -3e30f; sacc[mi][ni][r] = v; }
                m = fmaxf(m, v);
            }
#pragma unroll
            for (int off = 1; off < 16; off <<= 1) m = fmaxf(m, __shfl_xor(m, off, 64));
            if (c16 == 0) pmax[wn][wm * 48 + mi * 16 + kg * 4 + r] = m;
        }
    }
    __syncthreads();
    // exp + row-sum partials + write P~ (bf16) to swizzled LDS
#pragma unroll
    for (int mi = 0; mi < 3; ++mi) {
#pragma unroll
        for (int r = 0; r < 4; ++r) {
            int row = wm * 48 + mi * 16 + kg * 4 + r;
            float m = fmaxf(pmax[0][row], pmax[1][row]);
            float s = 0.f;
#pragma unroll
            for (int ni = 0; ni < 3; ++ni) {
                float pv = __expf(sacc[mi][ni][r] - m);
                sacc[mi][ni][r] = pv;
                s += pv;
            }
#pragma unroll
            for (int off = 1; off < 16; off <<= 1) s += __shfl_xor(s, off, 64);
            if (c16 == 0) psum[wn][row] = s;
#pragma unroll
            for (int ni = 0; ni < 3; ++ni) {
                int col = wn * 48 + ni * 16 + c16;
                Ps[row * 128 + ((((col >> 3) ^ (row & 7))) << 3) + (col & 7)] =
                    f2bf(sacc[mi][ni][r]);
            }
        }
    }
    __syncthreads();

    // ---- PV: wave (wm,wn) owns rows wm*48+48, cols wn*32+32 ----
    f32x4 oacc[3][2];
#pragma unroll
    for (int i = 0; i < 3; ++i)
#pragma unroll
        for (int j = 0; j < 2; ++j) oacc[i][j] = (f32x4){0.f, 0.f, 0.f, 0.f};
    {
        const char* Pc = (const char*)Ps;
        const char* Vc = (const char*)Vs;
#pragma unroll
        for (int ks = 0; ks < 3; ++ks) {
            bf16x8 pa[3], va[2];
#pragma unroll
            for (int mi = 0; mi < 3; ++mi) {
                int row = wm * 48 + mi * 16 + c16;
                pa[mi] = *(const bf16x8*)(Pc + row * 256 + (((ks * 4 + kg) ^ (row & 7)) << 4));
            }
#pragma unroll
            for (int ni = 0; ni < 2; ++ni) {
                int col = wn * 32 + ni * 16 + c16;
                va[ni] = *(const bf16x8*)(Vc + (ks * 4 + kg) * 1024 + col * 16);
            }
#pragma unroll
            for (int mi = 0; mi < 3; ++mi)
#pragma unroll
                for (int ni = 0; ni < 2; ++ni)
                    oacc[mi][ni] = __builtin_amdgcn_mfma_f32_16x16x32_bf16(
                        pa[mi], va[ni], oacc[mi][ni], 0, 0, 0);
        }
    }

    // ---- epilogue: normalize by row-sum, store ----
#pragma unroll
    for (int mi = 0; mi < 3; ++mi) {
#pragma unroll
        for (int r = 0; r < 4; ++r) {
            int row = wm * 48 + mi * 16 + kg * 4 + r;
            if (row < SEQL) {
                float inv = 1.0f / (psum[0][row] + psum[1][row]);
                size_t obase = (size_t)(b * SEQL + row) * DMODEL + h * HD;
#pragma unroll
                for (int ni = 0; ni < 2; ++ni) {
                    int col = wn * 32 + ni * 16 + c16;
                    o[obase + col] = f2bf(oacc[mi][ni][r] * inv);
                }
            }
        }
    }
}

// ----------------------------- small conv tail -----------------------------
__global__ void conv1_kernel(const float* __restrict__ x, const float* __restrict__ w,
                             const float* __restrict__ cb, const float* __restrict__ g,
                             const float* __restrict__ bb, const float* __restrict__ bm,
                             const float* __restrict__ bv, float* __restrict__ out) {
    int idx = blockIdx.x * blockDim.x + threadIdx.x;
    if (idx >= BATCH * 64 * 14) return;
    int t = idx % 14, o = (idx / 14) % 64, b = idx / (14 * 64);
    float acc = cb[o];
    const float* wo = w + (long)o * 128 * 8;
    const float* xb = x + (long)b * 128 * 35;
    for (int c = 0; c < 128; ++c) {
#pragma unroll
        for (int kk = 0; kk < 8; ++kk)
            acc += xb[c * 35 + 2 * t + kk] * wo[c * 8 + kk];
    }
    float y = (acc - bm[o]) * g[o] * rsqrtf(bv[o] + 1e-5f) + bb[o];
    out[idx] = fmaxf(y, 0.0f);
}

__global__ void conv2_kernel(const float* __restrict__ x, const float* __restrict__ w,
                             const float* __restrict__ cb, const float* __restrict__ g,
                             const float* __restrict__ bb, const float* __restrict__ bm,
                             const float* __restrict__ bv, float* __restrict__ out) {
    int idx = blockIdx.x * blockDim.x + threadIdx.x;
    if (idx >= BATCH * 32 * 5) return;
    int t = idx % 5, o = (idx / 5) % 32, b = idx / (5 * 32);
    float acc = cb[o];
    const float* wo = w + (long)o * 64 * 3;
    const float* xb = x + (long)b * 64 * 12;
    for (int c = 0; c < 64; ++c) {
#pragma unroll
        for (int kk = 0; kk < 3; ++kk)
            acc += xb[c * 12 + 2 * t + kk] * wo[c * 3 + kk];
    }
    float y = (acc - bm[o]) * g[o] * rsqrtf(bv[o] + 1e-5f) + bb[o];
    out[idx] = fmaxf(y, 0.0f);
}

__global__ void pool_kernel(const float* __restrict__ in, float* __restrict__ out,
                            int C, int Tin) {
    int Tout = Tin - 2;
    int idx = blockIdx.x * blockDim.x + threadIdx.x;
    if (idx >= BATCH * C * Tout) return;
    int t = idx % Tout;
    int co = idx / Tout;
    const float* p = in + (long)co * Tin + t;
    out[idx] = fmaxf(fmaxf(p[0], p[1]), p[2]);
}

__global__ __launch_bounds__(64) void head_kernel(
    const float* __restrict__ x, const float* __restrict__ w1,
    const float* __restrict__ b1, const float* __restrict__ w2,
    const float* __restrict__ b2, float* __restrict__ out) {
    int b = blockIdx.x;
    int j = threadIdx.x;
    float y = 0.f;
    if (j < 32) {
        float acc = b1[j];
        const float* xb = x + b * 96;
        for (int i = 0; i < 96; ++i) acc += xb[i] * w1[j * 96 + i];
        y = fmaxf(acc, 0.0f) * w2[j];
    }
#pragma unroll
    for (int o = 32; o > 0; o >>= 1) y += __shfl_down(y, o, 64);
    if (j == 0) out[b] = 1.0f / (1.0f + expf(-(y + b2[0])));
}

// ----------------------------- launch -----------------------------
extern "C" void kernel_launch(void* const* d_in, const int* in_sizes, int n_in,
                              void* d_out, int out_size, void* d_ws, size_t ws_size,
                              hipStream_t stream) {
    const int*   ids  = (const int*)d_in[0];
    const float* wemb = (const float*)d_in[1];
    const float* pemb = (const float*)d_in[2];
    const float* elng = (const float*)d_in[3];
    const float* elnb = (const float*)d_in[4];
    const float* wq = (const float*)d_in[5];
    const float* bq = (const float*)d_in[6];
    const float* wk = (const float*)d_in[7];
    const float* bk = (const float*)d_in[8];
    const float* wv = (const float*)d_in[9];
    const float* bv = (const float*)d_in[10];
    const float* wo = (const float*)d_in[11];
    const float* bo = (const float*)d_in[12];
    const float* ln1g = (const float*)d_in[13];
    const float* ln1b = (const float*)d_in[14];
    const float* w1 = (const float*)d_in[15];
    const float* b1 = (const float*)d_in[16];
    const float* w2 = (const float*)d_in[17];
    const float* b2 = (const float*)d_in[18];
    const float* ln2g = (const float*)d_in[19];
    const float* ln2b = (const float*)d_in[20];
    const float* c0w = (const float*)d_in[21];
    const float* c0b = (const float*)d_in[22];
    const float* g0 = (const float*)d_in[23];
    const float* bb0 = (const float*)d_in[24];
    const float* m0 = (const float*)d_in[25];
    const float* v0 = (const float*)d_in[26];
    const float* c1w = (const float*)d_in[27];
    const float* c1b = (const float*)d_in[28];
    const float* g1 = (const float*)d_in[29];
    const float* bb1 = (const float*)d_in[30];
    const float* m1 = (const float*)d_in[31];
    const float* v1 = (const float*)d_in[32];
    const float* c2w = (const float*)d_in[33];
    const float* c2b = (const float*)d_in[34];
    const float* g2 = (const float*)d_in[35];
    const float* bb2 = (const float*)d_in[36];
    const float* m2 = (const float*)d_in[37];
    const float* v2 = (const float*)d_in[38];
    const float* d1w = (const float*)d_in[39];
    const float* d1b = (const float*)d_in[40];
    const float* d2w = (const float*)d_in[41];
    const float* d2b = (const float*)d_in[42];
    (void)in_sizes; (void)n_in; (void)out_size;

    const size_t SZ = (size_t)NTOK * DMODEL;
    char* p = (char*)d_ws;
    float*  h    = (float*)p;  p += SZ * 4;
    ushort* hb   = (ushort*)p; p += SZ * 2;
    ushort* qkvb = (ushort*)p; p += (size_t)NTOK * 2304 * 2;
    ushort* ob   = (ushort*)p; p += SZ * 2;
    ushort* rb   = (ushort*)p; p += SZ * 2;
    ushort* qkvw = (ushort*)p; p += (size_t)DMODEL * 2304 * 2;
    ushort* wob  = (ushort*)p; p += (size_t)DMODEL * DMODEL * 2;
    ushort* w1b  = (ushort*)p; p += (size_t)DMODEL * FFDIM * 2;
    ushort* w2b  = (ushort*)p; p += (size_t)FFDIM * DMODEL * 2;
    float*  cbias= (float*)p;  p += 2304 * 4;
    ushort* wc0  = (ushort*)p; p += (size_t)8 * 96 * 128 * 8 * 2;
    float* c0 = (float*)p;  p += (size_t)BATCH * 128 * 37 * 4;
    float* p0 = (float*)p;  p += (size_t)BATCH * 128 * 35 * 4;
    float* c1 = (float*)p;  p += (size_t)BATCH * 64 * 14 * 4;
    float* p1 = (float*)p;  p += (size_t)BATCH * 64 * 12 * 4;
    float* c2 = (float*)p;  p += (size_t)BATCH * 32 * 5 * 4;
    float* p2 = (float*)p;  p += (size_t)BATCH * 32 * 3 * 4;
    ushort* ff = (ushort*)p;
    size_t used = (size_t)(p - (char*)d_ws);
    bool full = (used + (size_t)NTOK * FFDIM * 2) <= ws_size;
    const int FCH = full ? NTOK : FFCH;
    const int nch = full ? 1 : 3;

    embed_ln_kernel<<<NTOK, 256, 0, stream>>>(ids, wemb, pemb, elng, elnb, h, hb);
    convw_c0<<<(128 * 768 * 8 + 255) / 256, 256, 0, stream>>>(c0w, wc0);

    const int NWG_QKV = (NTOK / 128) * (2304 / 128);   // 2916
    const int NWG_WO  = (NTOK / 128) * (DMODEL / 128); // 972
    const int NWG_F1  = (FCH / 128) * (FFDIM / 128);
    const int NWG_F2  = (FCH / 128) * (DMODEL / 128);

    for (int l = 0; l < NLAYER; ++l) {
        convw_layer<<<4096, 256, 0, stream>>>(
            wq + (size_t)l * SQ1, wk + (size_t)l * SQ1, wv + (size_t)l * SQ1,
            wo + (size_t)l * SQ1, w1 + (size_t)l * SQ2, w2 + (size_t)l * SQ2,
            bq + (size_t)l * DMODEL, bk + (size_t)l * DMODEL, bv + (size_t)l * DMODEL,
            qkvw, wob, w1b, w2b, cbias);

        gemm_bf16<0><<<NWG_QKV, 256, 0, stream>>>(hb, qkvw, cbias, qkvb,
                                                  NTOK, 2304, DMODEL, 0.125f, 768, 18);
        attn_mfma<<<BATCH * NH, 256, 0, stream>>>(qkvb, ob);
        gemm_bf16<0><<<NWG_WO, 256, 0, stream>>>(ob, wob, bo + (size_t)l * DMODEL, rb,
                                                 NTOK, DMODEL, DMODEL, 1.0f, 0, 6);
        add_ln_kernel<<<NTOK, 192, 0, stream>>>(h, rb, ln1g + (size_t)l * DMODEL,
                                                ln1b + (size_t)l * DMODEL, hb);
        for (int ch = 0; ch < nch; ++ch) {
            const ushort* hc = hb + (size_t)ch * FCH * DMODEL;
            ushort* rc = rb + (size_t)ch * FCH * DMODEL;
            gemm_bf16<1><<<NWG_F1, 256, 0, stream>>>(hc, w1b, b1 + (size_t)l * FFDIM, ff,
                                                     FCH, FFDIM, DMODEL, 1.0f, 0, FFDIM / 128);
            gemm_bf16<0><<<NWG_F2, 256, 0, stream>>>(ff, w2b, b2 + (size_t)l * DMODEL, rc,
                                                     FCH, DMODEL, FFDIM, 1.0f, 0, DMODEL / 128);
        }
        add_ln_kernel<<<NTOK, 192, 0, stream>>>(h, rb, ln2g + (size_t)l * DMODEL,
                                                ln2b + (size_t)l * DMODEL, hb);
    }

    // CNN / MLP head
    {
        conv0_gemm<<<74, 256, 0, stream>>>(hb, wc0, c0b, g0, bb0, m0, v0, c0);
        int n = BATCH * 128 * 35;
        pool_kernel<<<(n + 255) / 256, 256, 0, stream>>>(c0, p0, 128, 37);
        n = BATCH * 64 * 14;
        conv1_kernel<<<(n + 255) / 256, 256, 0, stream>>>(p0, c1w, c1b, g1, bb1, m1, v1, c1);
        n = BATCH * 64 * 12;
        pool_kernel<<<(n + 255) / 256, 256, 0, stream>>>(c1, p1, 64, 14);
        n = BATCH * 32 * 5;
        conv2_kernel<<<(n + 255) / 256, 256, 0, stream>>>(p1, c2w, c2b, g2, bb2, m2, v2, c2);
        n = BATCH * 32 * 3;
        pool_kernel<<<(n + 255) / 256, 256, 0, stream>>>(c2, p2, 32, 5);
        head_kernel<<<BATCH, 64, 0, stream>>>(p2, d1w, d1b, d2w, d2b, (float*)d_out);
    }
}